// Round 9
// baseline (520.249 us; speedup 1.0000x reference)
//
#include <hip/hip_runtime.h>
#include <hip/hip_bf16.h>

typedef unsigned short u16;
typedef __bf16 bf8v __attribute__((ext_vector_type(8)));
typedef float f4v __attribute__((ext_vector_type(4)));

__device__ __forceinline__ float b2f(u16 v) {
  union { unsigned u; float f; } x; x.u = ((unsigned)v) << 16; return x.f;
}
__device__ __forceinline__ u16 f2b(float f) {
  union { float f; unsigned u; } x; x.f = f;
  unsigned r = (x.u + 0x7FFFu + ((x.u >> 16) & 1u)) >> 16;
  return (u16)r;
}
__device__ __forceinline__ unsigned pkbf(float a, float b) {
  union { __hip_bfloat162 h; unsigned u; } c;
  c.h = __float22bfloat162_rn(make_float2(a, b));
  return c.u;
}
__device__ __forceinline__ void up2(unsigned u, float& lo, float& hi) {
  union { unsigned x; float f; } a, b;
  a.x = u << 16; b.x = u & 0xffff0000u; lo = a.f; hi = b.f;
}

// ---------------------------------------------------------------------------
// Fragment-major weight layout: for weight W[k=0..255][n], tile T=n>>4:
// frag[((T*8+kt)*64+lane)*8 + j] = bf16(W[kt*32+(lane>>4)*8+j][T*16+(lane&15)])
// ---------------------------------------------------------------------------
#define NFRAG 19
struct PreArgs {
  const float* fsrc[NFRAG];
  u16* fdst[NFRAG];
  int fstride[NFRAG];
  int fbase[NFRAG + 1];
  int fragTiles, hBase, prepBid, q1Bid;
  const float *x, *ginW, *ginb;
  u16* h_bf;
  const float *mbk, *mbv, *mbq, *S, *mWq;
  float *bkv0, *bqkv1, *bqkv2;
  u16* q1b;
};

__global__ __launch_bounds__(256) void k_pre(PreArgs a) {
  __shared__ u16 ld[256 * 20];
  __shared__ float xs[4][48];
  __shared__ float Ss[4096];
  const int bid = blockIdx.x, t = threadIdx.x;

  if (bid < a.fragTiles) {
    int j = 0;
    while (j + 1 < NFRAG && a.fbase[j + 1] <= bid) j++;
    const int localT = bid - a.fbase[j];
    const float* src = a.fsrc[j];
    const int Ns = a.fstride[j];
    const int n0 = localT * 16;
    {
      const float* s = src + (size_t)t * Ns + n0;
      const float4 v0 = ((const float4*)s)[0], v1 = ((const float4*)s)[1];
      const float4 v2 = ((const float4*)s)[2], v3 = ((const float4*)s)[3];
      unsigned* row = (unsigned*)(ld + t * 20);
      row[0] = pkbf(v0.x, v0.y); row[1] = pkbf(v0.z, v0.w);
      row[2] = pkbf(v1.x, v1.y); row[3] = pkbf(v1.z, v1.w);
      row[4] = pkbf(v2.x, v2.y); row[5] = pkbf(v2.z, v2.w);
      row[6] = pkbf(v3.x, v3.y); row[7] = pkbf(v3.z, v3.w);
    }
    __syncthreads();
    u16* dst = a.fdst[j] + (size_t)localT * 4096;
#pragma unroll
    for (int s2 = 0; s2 < 2; s2++) {
      const int o = t * 2 + s2, kt = o >> 6, lane = o & 63;
      const int nlo = lane & 15, bk = kt * 32 + ((lane >> 4) << 3);
      union { u16 h[8]; uint4 q; } pk;
#pragma unroll
      for (int j2 = 0; j2 < 8; j2++) pk.h[j2] = ld[(bk + j2) * 20 + nlo];
      *(uint4*)(dst + (size_t)(kt * 64 + lane) * 8) = pk.q;
    }
    return;
  }
  if (bid >= a.hBase && bid < a.hBase + 256) {
    const int row0 = (bid - a.hBase) * 4;
    if (t < 192) {
      const int rr = t / 48, k = t % 48;
      xs[rr][k] = a.x[(size_t)(row0 + rr) * 48 + k];
    }
    __syncthreads();
    const float bias = a.ginb[t];
    float acc[4] = {bias, bias, bias, bias};
    for (int k = 0; k < 48; k++) {
      const float w = a.ginW[(size_t)k * 256 + t];
#pragma unroll
      for (int rr = 0; rr < 4; rr++) acc[rr] += xs[rr][k] * w;
    }
#pragma unroll
    for (int rr = 0; rr < 4; rr++) a.h_bf[(size_t)(row0 + rr) * 256 + t] = f2b(acc[rr]);
    return;
  }
  if (bid == a.prepBid) {
    a.bkv0[t] = a.mbk[t]; a.bkv0[256 + t] = a.mbv[t];
    a.bqkv1[t] = a.mbq[256 + t]; a.bqkv1[256 + t] = a.mbk[256 + t]; a.bqkv1[512 + t] = a.mbv[256 + t];
    a.bqkv2[t] = a.mbq[512 + t]; a.bqkv2[256 + t] = a.mbk[512 + t]; a.bqkv2[512 + t] = a.mbv[512 + t];
    return;
  }
  if (bid == a.q1Bid) {
    for (int idx = t; idx < 4096; idx += 256) Ss[idx] = a.S[idx];
    __syncthreads();
    float acc[16];
#pragma unroll
    for (int r = 0; r < 16; r++) acc[r] = 0.f;
    for (int k = 0; k < 256; k++) {
      const float w = a.mWq[(size_t)k * 256 + t];
#pragma unroll
      for (int r = 0; r < 16; r++) acc[r] += Ss[r * 256 + k] * w;
    }
    const float bq = a.mbq[t];
#pragma unroll
    for (int r = 0; r < 16; r++) a.q1b[r * 256 + t] = f2b(acc[r] + bq);
    return;
  }
}

// ---------------------------------------------------------------------------
// hWiWj GEMM
// ---------------------------------------------------------------------------
__global__ __launch_bounds__(256) void k_wiwj(
    const u16* __restrict__ h, const u16* __restrict__ frag, float* __restrict__ out) {
  __shared__ __align__(16) u16 As[64 * 264];
  const int t = threadIdx.x, lane = t & 63, wv = t >> 6;
  const int m0 = blockIdx.x * 64, n0 = blockIdx.y * 128;
  {
    const int row = t >> 2, ch = t & 3;
#pragma unroll
    for (int s = 0; s < 8; s++)
      *(uint4*)(As + row * 264 + ch * 64 + s * 8) =
          *(const uint4*)(h + (size_t)(m0 + row) * 256 + ch * 64 + s * 8);
  }
  __syncthreads();
  f4v acc[4][2];
#pragma unroll
  for (int mt = 0; mt < 4; mt++)
#pragma unroll
    for (int nt = 0; nt < 2; nt++) acc[mt][nt] = (f4v){0.f, 0.f, 0.f, 0.f};
  const int Tw = (n0 >> 4) + wv * 2;
#pragma unroll
  for (int kt = 0; kt < 8; kt++) {
    bf8v af[4], bf[2];
#pragma unroll
    for (int mt = 0; mt < 4; mt++)
      af[mt] = *(const bf8v*)(As + (mt * 16 + (lane & 15)) * 264 + kt * 32 + ((lane >> 4) << 3));
#pragma unroll
    for (int nt = 0; nt < 2; nt++)
      bf[nt] = *(const bf8v*)(frag + ((size_t)((Tw + nt) * 8 + kt) * 64 + lane) * 8);
#pragma unroll
    for (int mt = 0; mt < 4; mt++)
#pragma unroll
      for (int nt = 0; nt < 2; nt++)
        acc[mt][nt] = __builtin_amdgcn_mfma_f32_16x16x32_bf16(af[mt], bf[nt], acc[mt][nt], 0, 0, 0);
  }
#pragma unroll
  for (int mt = 0; mt < 4; mt++)
#pragma unroll
    for (int nt = 0; nt < 2; nt++) {
      const int n = n0 + wv * 32 + nt * 16 + (lane & 15);
      const int mb = m0 + mt * 16 + ((lane >> 4) << 2);
#pragma unroll
      for (int r = 0; r < 4; r++) out[(size_t)(mb + r) * 512 + n] = acc[mt][nt][r];
    }
}

// ---------------------------------------------------------------------------
// Edge MLP + masked aggregation. 3 blocks/CU for latency hiding.
// ---------------------------------------------------------------------------
__global__ __launch_bounds__(256, 3) void k_edge(
    const float* __restrict__ hWiWj, const float* __restrict__ adj,
    const float* __restrict__ geb1, const u16* __restrict__ fragW2,
    const float* __restrict__ geb2, u16* __restrict__ aggB) {
  __shared__ __align__(16) u16 As[64 * 264];
  __shared__ float hi[256];
  __shared__ int jlist[256];
  __shared__ int cnt;
  const int t = threadIdx.x, lane = t & 63, wv = t >> 6;
  const int b = blockIdx.x >> 8, i = blockIdx.x & 255;
  if (t == 0) cnt = 0;
  __syncthreads();
  {
    const float a = adj[(size_t)(b * 256 + i) * 256 + t];
    hi[t] = hWiWj[(size_t)(b * 256 + i) * 512 + t] + geb1[t];
    if (a != 0.f) { const int p = atomicAdd(&cnt, 1); jlist[p] = t; }
  }
  __syncthreads();
  const int nact = cnt;
  if (nact == 0) {
    if (lane < 16) {
#pragma unroll
      for (int nt = 0; nt < 4; nt++)
        aggB[(size_t)(b * 256 + i) * 256 + wv * 64 + nt * 16 + lane] = 0;
    }
    return;
  }
  const int nch = (nact + 63) >> 6;
  float bias2[4];
#pragma unroll
  for (int nt = 0; nt < 4; nt++) bias2[nt] = geb2[wv * 64 + nt * 16 + (lane & 15)];
  float aggAcc[4] = {0.f, 0.f, 0.f, 0.f};
  const u16* fw = fragW2 + lane * 8;

  for (int c = 0; c < nch; c++) {
    const int rows = min(64, nact - c * 64);
    {
      const int r = t >> 2, q = t & 3;
      const bool valid = (r < rows);
      const int j = valid ? jlist[c * 64 + r] : jlist[0];
      const float4* s4 = (const float4*)(hWiWj + (size_t)(b * 256 + j) * 512 + 256 + q * 64);
      u16* dstrow = As + r * 264 + q * 64;
#pragma unroll
      for (int ii = 0; ii < 8; ii++) {
        const float4 v0 = s4[ii * 2];
        const float4 v1 = s4[ii * 2 + 1];
        const int k = q * 64 + ii * 8;
        uint4 qd;
        qd.x = pkbf(fmaxf(v0.x + hi[k + 0], 0.f), fmaxf(v0.y + hi[k + 1], 0.f));
        qd.y = pkbf(fmaxf(v0.z + hi[k + 2], 0.f), fmaxf(v0.w + hi[k + 3], 0.f));
        qd.z = pkbf(fmaxf(v1.x + hi[k + 4], 0.f), fmaxf(v1.y + hi[k + 5], 0.f));
        qd.w = pkbf(fmaxf(v1.z + hi[k + 6], 0.f), fmaxf(v1.w + hi[k + 7], 0.f));
        *(uint4*)(dstrow + ii * 8) = qd;
      }
    }
    __syncthreads();
    f4v acc[4][4];
#pragma unroll
    for (int jt = 0; jt < 4; jt++)
#pragma unroll
      for (int nt = 0; nt < 4; nt++) acc[jt][nt] = (f4v){0.f, 0.f, 0.f, 0.f};
    bf8v bcur[4];
#pragma unroll
    for (int nt = 0; nt < 4; nt++)
      bcur[nt] = *(const bf8v*)(fw + (size_t)((wv * 4 + nt) * 8 + 0) * 512);
#pragma unroll
    for (int kt = 0; kt < 8; kt++) {
      bf8v bnxt[4];
      if (kt < 7) {
#pragma unroll
        for (int nt = 0; nt < 4; nt++)
          bnxt[nt] = *(const bf8v*)(fw + (size_t)((wv * 4 + nt) * 8 + kt + 1) * 512);
      }
      bf8v af[4];
#pragma unroll
      for (int jt = 0; jt < 4; jt++)
        af[jt] = *(const bf8v*)(As + (jt * 16 + (lane & 15)) * 264 + kt * 32 + ((lane >> 4) << 3));
#pragma unroll
      for (int nt = 0; nt < 4; nt++)
#pragma unroll
        for (int jt = 0; jt < 4; jt++)
          acc[jt][nt] = __builtin_amdgcn_mfma_f32_16x16x32_bf16(af[jt], bcur[nt], acc[jt][nt], 0, 0, 0);
      if (kt < 7) {
#pragma unroll
        for (int nt = 0; nt < 4; nt++) bcur[nt] = bnxt[nt];
      }
    }
    const int rbase = (lane >> 4) * 4;
#pragma unroll
    for (int nt = 0; nt < 4; nt++) {
      float s = 0.f;
#pragma unroll
      for (int jt = 0; jt < 4; jt++) {
        const int r0 = jt * 16 + rbase;
#pragma unroll
        for (int r = 0; r < 4; r++) {
          const float e = fmaxf(acc[jt][nt][r] + bias2[nt], 0.f);
          s += (r0 + r < rows) ? e : 0.f;
        }
      }
      s += __shfl_xor(s, 16);
      s += __shfl_xor(s, 32);
      aggAcc[nt] += s;
    }
    __syncthreads();
  }
  if (lane < 16) {
#pragma unroll
    for (int nt = 0; nt < 4; nt++) {
      const int n = wv * 64 + nt * 16 + lane;
      aggB[(size_t)(b * 256 + i) * 256 + n] = f2b(aggAcc[nt]);
    }
  }
}

// ---------------------------------------------------------------------------
// Fused tail v3: 4 blocks x 1024 threads, one block per batch b.
// ZERO grid barriers — everything after agg is b-closed; only __syncthreads.
// ---------------------------------------------------------------------------

// M=32 GEMM (squad = 256 threads), A in LDS (stride 264), frag-major B.
__device__ void g32(const u16* Al, const u16* frag, const float* bias, int relu,
                    u16* Ol, int t) {
  const int lane = t & 63, wv = t >> 6;
  f4v acc[2][4];
#pragma unroll
  for (int mt = 0; mt < 2; mt++)
#pragma unroll
    for (int nt = 0; nt < 4; nt++) acc[mt][nt] = (f4v){0.f, 0.f, 0.f, 0.f};
#pragma unroll
  for (int kt = 0; kt < 8; kt++) {
    bf8v af[2], bf[4];
#pragma unroll
    for (int mt = 0; mt < 2; mt++)
      af[mt] = *(const bf8v*)(Al + (mt * 16 + (lane & 15)) * 264 + kt * 32 + ((lane >> 4) << 3));
#pragma unroll
    for (int nt = 0; nt < 4; nt++)
      bf[nt] = *(const bf8v*)(frag + ((size_t)((wv * 4 + nt) * 8 + kt) * 64 + lane) * 8);
#pragma unroll
    for (int mt = 0; mt < 2; mt++)
#pragma unroll
      for (int nt = 0; nt < 4; nt++)
        acc[mt][nt] = __builtin_amdgcn_mfma_f32_16x16x32_bf16(af[mt], bf[nt], acc[mt][nt], 0, 0, 0);
  }
#pragma unroll
  for (int mt = 0; mt < 2; mt++)
#pragma unroll
    for (int nt = 0; nt < 4; nt++) {
      const int col = wv * 64 + nt * 16 + (lane & 15);
      const float bv = bias[col];
#pragma unroll
      for (int r = 0; r < 4; r++) {
        const int row = mt * 16 + ((lane >> 4) << 2) + r;
        float v = acc[mt][nt][r] + bv;
        if (relu) v = fmaxf(v, 0.f);
        Ol[row * 264 + col] = f2b(v);
      }
    }
}

// M=32, N=512 GEMM -> global bf16 (kv1)
__device__ void g32kv(const u16* Al, const u16* frag, const float* bias,
                      u16* outG, int t) {
  const int lane = t & 63, wv = t >> 6;
  f4v acc[2][8];
#pragma unroll
  for (int mt = 0; mt < 2; mt++)
#pragma unroll
    for (int nt = 0; nt < 8; nt++) acc[mt][nt] = (f4v){0.f, 0.f, 0.f, 0.f};
#pragma unroll
  for (int kt = 0; kt < 8; kt++) {
    bf8v af[2];
#pragma unroll
    for (int mt = 0; mt < 2; mt++)
      af[mt] = *(const bf8v*)(Al + (mt * 16 + (lane & 15)) * 264 + kt * 32 + ((lane >> 4) << 3));
#pragma unroll
    for (int nt = 0; nt < 8; nt++) {
      const bf8v bf = *(const bf8v*)(frag + ((size_t)((wv * 8 + nt) * 8 + kt) * 64 + lane) * 8);
#pragma unroll
      for (int mt = 0; mt < 2; mt++)
        acc[mt][nt] = __builtin_amdgcn_mfma_f32_16x16x32_bf16(af[mt], bf, acc[mt][nt], 0, 0, 0);
    }
  }
#pragma unroll
  for (int mt = 0; mt < 2; mt++)
#pragma unroll
    for (int nt = 0; nt < 8; nt++) {
      const int col = wv * 128 + nt * 16 + (lane & 15);
      const float bv = bias[col];
#pragma unroll
      for (int r = 0; r < 4; r++) {
        const int row = mt * 16 + ((lane >> 4) << 2) + r;
        outG[(size_t)row * 512 + col] = f2b(acc[mt][nt][r] + bv);
      }
    }
}

// attn1 (Lk=256), one (b,hd) per squad; V staged as bf16 in LDS.
__device__ void attn_squad(const u16* __restrict__ q1b, const u16* __restrict__ kv1,
                           float* __restrict__ o1f, u16* __restrict__ o1b,
                           int b, int hd, float* qs, float* sc, u16* vsB, int st) {
  const int lane = st & 63, wv = st >> 6;
  if (st < 64) {
    const int row = st >> 2, part = st & 3;
    const uint4 q4 = *(const uint4*)(q1b + (size_t)row * 256 + hd * 32 + part * 8);
    float f0, f1, f2, f3, f4, f5, f6, f7;
    up2(q4.x, f0, f1); up2(q4.y, f2, f3); up2(q4.z, f4, f5); up2(q4.w, f6, f7);
    float4* d = (float4*)(qs + row * 32 + part * 8);
    d[0] = make_float4(f0, f1, f2, f3);
    d[1] = make_float4(f4, f5, f6, f7);
  }
  for (int idx = st; idx < 1024; idx += 256) {  // V copy (already bf16)
    const int row = idx >> 2, part = idx & 3;
    *(uint4*)(vsB + row * 32 + part * 8) =
        *(const uint4*)(kv1 + (size_t)(b * 256 + row) * 512 + 256 + hd * 32 + part * 8);
  }
  __syncthreads();
  {
    float kv[32];
    const uint4* kp = (const uint4*)(kv1 + (size_t)(b * 256 + st) * 512 + hd * 32);
#pragma unroll
    for (int c4 = 0; c4 < 4; c4++) {
      const uint4 k4 = kp[c4];
      up2(k4.x, kv[c4 * 8 + 0], kv[c4 * 8 + 1]);
      up2(k4.y, kv[c4 * 8 + 2], kv[c4 * 8 + 3]);
      up2(k4.z, kv[c4 * 8 + 4], kv[c4 * 8 + 5]);
      up2(k4.w, kv[c4 * 8 + 6], kv[c4 * 8 + 7]);
    }
    for (int r = 0; r < 16; r++) {
      float s = 0.f;
#pragma unroll
      for (int d = 0; d < 32; d++) s += qs[r * 32 + d] * kv[d];
      sc[r * 256 + st] = s * 0.0625f;
    }
  }
  __syncthreads();
  for (int r = wv * 4; r < wv * 4 + 4; r++) {
    float v[4];
    float mx = -1e30f;
#pragma unroll
    for (int q2 = 0; q2 < 4; q2++) {
      v[q2] = sc[r * 256 + lane + q2 * 64];
      mx = fmaxf(mx, v[q2]);
    }
    for (int off = 32; off; off >>= 1) mx = fmaxf(mx, __shfl_xor(mx, off));
    float sum = 0.f;
#pragma unroll
    for (int q2 = 0; q2 < 4; q2++) { v[q2] = __expf(v[q2] - mx); sum += v[q2]; }
    for (int off = 32; off; off >>= 1) sum += __shfl_xor(sum, off);
    const float inv = 1.f / sum;
#pragma unroll
    for (int q2 = 0; q2 < 4; q2++) sc[r * 256 + lane + q2 * 64] = v[q2] * inv;
  }
  __syncthreads();
  const int r0 = st >> 5, d = st & 31;
  float a0 = qs[r0 * 32 + d], a1 = qs[(r0 + 8) * 32 + d];
#pragma unroll 4
  for (int j = 0; j < 256; j++) {
    const float vv = b2f(vsB[j * 32 + d]);
    a0 += sc[r0 * 256 + j] * vv;
    a1 += sc[(r0 + 8) * 256 + j] * vv;
  }
  const int c0 = hd * 32 + d;
  o1f[(size_t)(b * 16 + r0) * 256 + c0] = a0;
  o1b[(size_t)(b * 16 + r0) * 256 + c0] = f2b(a0);
  o1f[(size_t)(b * 16 + r0 + 8) * 256 + c0] = a1;
  o1b[(size_t)(b * 16 + r0 + 8) * 256 + c0] = f2b(a1);
}

// Wave-level M=16 projections (phase 3), A-frag sources vary.
__device__ void wprojG(const u16* __restrict__ o1b, const float* __restrict__ o1f,
                       const u16* __restrict__ frag, const float* __restrict__ bias,
                       u16* actL, float* residL, int b, int T, int lane) {
  f4v acc = (f4v){0.f, 0.f, 0.f, 0.f};
  const u16* abase = o1b + (size_t)(b * 16 + (lane & 15)) * 256 + ((lane >> 4) << 3);
  const u16* fbase = frag + ((size_t)(T * 8) * 64 + lane) * 8;
#pragma unroll
  for (int kt = 0; kt < 8; kt++)
    acc = __builtin_amdgcn_mfma_f32_16x16x32_bf16(*(const bf8v*)(abase + kt * 32),
                                                  *(const bf8v*)(fbase + (size_t)kt * 512), acc, 0, 0, 0);
  const int col = T * 16 + (lane & 15);
  const float bv = bias[col];
#pragma unroll
  for (int r = 0; r < 4; r++) {
    const int row = ((lane >> 4) << 2) + r;
    const float v = fmaxf(acc[r] + bv, 0.f) + o1f[(size_t)(b * 16 + row) * 256 + col];
    residL[row * 256 + col] = v;
    actL[row * 264 + col] = f2b(v);
  }
}

__device__ void wprojQ(const u16* actL, const u16* __restrict__ frag,
                       const float* __restrict__ bias, u16* qkvL, int T, int lane) {
  f4v acc = (f4v){0.f, 0.f, 0.f, 0.f};
  const u16* abase = actL + (lane & 15) * 264 + ((lane >> 4) << 3);
  const u16* fbase = frag + ((size_t)(T * 8) * 64 + lane) * 8;
#pragma unroll
  for (int kt = 0; kt < 8; kt++)
    acc = __builtin_amdgcn_mfma_f32_16x16x32_bf16(*(const bf8v*)(abase + kt * 32),
                                                  *(const bf8v*)(fbase + (size_t)kt * 512), acc, 0, 0, 0);
  const int col = T * 16 + (lane & 15);
  const float bv = bias[col];
#pragma unroll
  for (int r = 0; r < 4; r++) {
    const int row = ((lane >> 4) << 2) + r;
    qkvL[row * 776 + col] = f2b(acc[r] + bv);
  }
}

__device__ void wprojR(const u16* actIn, const u16* __restrict__ frag,
                       const float* __restrict__ bias, u16* actOut, float* residL,
                       int T, int lane) {
  f4v acc = (f4v){0.f, 0.f, 0.f, 0.f};
  const u16* abase = actIn + (lane & 15) * 264 + ((lane >> 4) << 3);
  const u16* fbase = frag + ((size_t)(T * 8) * 64 + lane) * 8;
#pragma unroll
  for (int kt = 0; kt < 8; kt++)
    acc = __builtin_amdgcn_mfma_f32_16x16x32_bf16(*(const bf8v*)(abase + kt * 32),
                                                  *(const bf8v*)(fbase + (size_t)kt * 512), acc, 0, 0, 0);
  const int col = T * 16 + (lane & 15);
  const float bv = bias[col];
#pragma unroll
  for (int r = 0; r < 4; r++) {
    const int row = ((lane >> 4) << 2) + r;
    const float v = fmaxf(acc[r] + bv, 0.f) + residL[row * 256 + col];
    residL[row * 256 + col] = v;
    actOut[row * 264 + col] = f2b(v);
  }
}

__device__ void wprojF(const u16* actL, const u16* __restrict__ frag,
                       const float* __restrict__ bias, float* __restrict__ outG,
                       int T, int lane) {
  f4v acc = (f4v){0.f, 0.f, 0.f, 0.f};
  const u16* abase = actL + (lane & 15) * 264 + ((lane >> 4) << 3);
  const u16* fbase = frag + ((size_t)(T * 8) * 64 + lane) * 8;
#pragma unroll
  for (int kt = 0; kt < 8; kt++)
    acc = __builtin_amdgcn_mfma_f32_16x16x32_bf16(*(const bf8v*)(abase + kt * 32),
                                                  *(const bf8v*)(fbase + (size_t)kt * 512), acc, 0, 0, 0);
  const int col = T * 16 + (lane & 15);
  const float bv = bias[col];
#pragma unroll
  for (int r = 0; r < 4; r++) {
    const int row = ((lane >> 4) << 2) + r;
    outG[(size_t)row * 384 + col] = acc[r] + bv;
  }
}

// In-LDS attention (Lk=16), one head per wave. qkvL stride 776.
__device__ void attnB(const u16* qkvL, float* residL, u16* actOut, float* ps,
                      int hd, int lane) {
  const int r = lane & 15, cg = lane >> 4;
  float qv[32];
  {
    const uint4* qp = (const uint4*)(qkvL + r * 776 + hd * 32);
#pragma unroll
    for (int c4 = 0; c4 < 4; c4++) {
      const uint4 q4 = qp[c4];
      up2(q4.x, qv[c4 * 8 + 0], qv[c4 * 8 + 1]);
      up2(q4.y, qv[c4 * 8 + 2], qv[c4 * 8 + 3]);
      up2(q4.z, qv[c4 * 8 + 4], qv[c4 * 8 + 5]);
      up2(q4.w, qv[c4 * 8 + 6], qv[c4 * 8 + 7]);
    }
  }
  float p[4];
#pragma unroll
  for (int c = 0; c < 4; c++) {
    const int cc = cg * 4 + c;
    const uint4* kp = (const uint4*)(qkvL + cc * 776 + 256 + hd * 32);
    float s = 0.f;
#pragma unroll
    for (int c4 = 0; c4 < 4; c4++) {
      const uint4 k4 = kp[c4];
      float k0, k1;
      up2(k4.x, k0, k1); s += qv[c4 * 8 + 0] * k0 + qv[c4 * 8 + 1] * k1;
      up2(k4.y, k0, k1); s += qv[c4 * 8 + 2] * k0 + qv[c4 * 8 + 3] * k1;
      up2(k4.z, k0, k1); s += qv[c4 * 8 + 4] * k0 + qv[c4 * 8 + 5] * k1;
      up2(k4.w, k0, k1); s += qv[c4 * 8 + 6] * k0 + qv[c4 * 8 + 7] * k1;
    }
    p[c] = s * 0.0625f;
  }
  float mx = fmaxf(fmaxf(p[0], p[1]), fmaxf(p[2], p[3]));
  mx = fmaxf(mx, __shfl_xor(mx, 16));
  mx = fmaxf(mx, __shfl_xor(mx, 32));
  float sum = 0.f;
#pragma unroll
  for (int c = 0; c < 4; c++) { p[c] = __expf(p[c] - mx); sum += p[c]; }
  sum += __shfl_xor(sum, 16);
  sum += __shfl_xor(sum, 32);
  const float inv = 1.f / sum;
#pragma unroll
  for (int c = 0; c < 4; c++) ps[r * 16 + cg * 4 + c] = p[c] * inv;
  float o[8];
#pragma unroll
  for (int j = 0; j < 8; j++) o[j] = qv[cg * 8 + j];
#pragma unroll
  for (int c = 0; c < 16; c++) {
    const float pv = ps[r * 16 + c];
    const uint4 v4 = *(const uint4*)(qkvL + c * 776 + 512 + hd * 32 + cg * 8);
    float v0, v1;
    up2(v4.x, v0, v1); o[0] += pv * v0; o[1] += pv * v1;
    up2(v4.y, v0, v1); o[2] += pv * v0; o[3] += pv * v1;
    up2(v4.z, v0, v1); o[4] += pv * v0; o[5] += pv * v1;
    up2(v4.w, v0, v1); o[6] += pv * v0; o[7] += pv * v1;
  }
  const int col0 = hd * 32 + cg * 8;
#pragma unroll
  for (int j = 0; j < 8; j++) residL[r * 256 + col0 + j] = o[j];
  unsigned* ob = (unsigned*)(actOut + r * 264 + col0);
  ob[0] = pkbf(o[0], o[1]); ob[1] = pkbf(o[2], o[3]);
  ob[2] = pkbf(o[4], o[5]); ob[3] = pkbf(o[6], o[7]);
}

struct TailArgs {
  const u16 *agg, *fGn1, *fGn2, *fGo, *fKV0, *fQKV1, *fQKV2, *fO0, *fO1, *fO2, *fFin, *q1b;
  const float *gnb1, *gnb2, *gob, *bkv0, *bqkv1, *bqkv2, *mbo, *finb;
  u16 *kv1, *o1b;
  float *o1f, *outF;
};

__global__ __launch_bounds__(1024) void k_tail(TailArgs a) {
  __shared__ __align__(16) char smem[139264];
  const int b = blockIdx.x, t = threadIdx.x;
  const int sq = t >> 8, st = t & 255;
  const int lane = t & 63, w = t >> 6;

  {  // ---- phase 1: node MLP + kv1, squads do 2 x 32-row units ----
    u16* act0 = (u16*)(smem + sq * 33792);
    u16* act1 = act0 + 8448;
    for (int c = 0; c < 2; c++) {
      const int r0 = b * 256 + (sq + 4 * c) * 32;
#pragma unroll
      for (int s = 0; s < 4; s++) {
        const int u = st * 4 + s, row = u >> 5, ch = u & 31;
        *(uint4*)(act0 + row * 264 + ch * 8) =
            *(const uint4*)(a.agg + (size_t)(r0 + row) * 256 + ch * 8);
      }
      __syncthreads();
      g32(act0, a.fGn1, a.gnb1, 1, act1, st); __syncthreads();
      g32(act1, a.fGn2, a.gnb2, 1, act0, st); __syncthreads();
      g32(act0, a.fGo, a.gob, 0, act1, st); __syncthreads();
      g32kv(act1, a.fKV0, a.bkv0, a.kv1 + (size_t)r0 * 512, st);
      __syncthreads();
    }
  }
  {  // ---- phase 2: attn1, squads do 2 heads each ----
    float* qs = (float*)(smem + sq * 34816);
    float* sc = (float*)(smem + sq * 34816 + 2048);
    u16* vsB = (u16*)(smem + sq * 34816 + 18432);
    for (int c = 0; c < 2; c++) {
      attn_squad(a.q1b, a.kv1, a.o1f, a.o1b, b, sq * 2 + c, qs, sc, vsB, st);
      __syncthreads();
    }
  }
  // ---- phase 3: mab2 + mab3 + final, all in LDS, 16 waves ----
  u16* act0 = (u16*)smem;
  u16* act1 = (u16*)(smem + 8448);
  u16* qkvL = (u16*)(smem + 16896);
  float* residL = (float*)(smem + 41728);
  float* psL = (float*)(smem + 58112);

  wprojG(a.o1b, a.o1f, a.fO0, a.mbo, act0, residL, b, w, lane);
  __syncthreads();
  for (int T = w; T < 48; T += 16) wprojQ(act0, a.fQKV1, a.bqkv1, qkvL, T, lane);
  __syncthreads();
  if (w < 8) attnB(qkvL, residL, act1, psL + w * 256, w, lane);
  __syncthreads();
  wprojR(act1, a.fO1, a.mbo + 256, act0, residL, w, lane);
  __syncthreads();
  for (int T = w; T < 48; T += 16) wprojQ(act0, a.fQKV2, a.bqkv2, qkvL, T, lane);
  __syncthreads();
  if (w < 8) attnB(qkvL, residL, act1, psL + w * 256, w, lane);
  __syncthreads();
  wprojR(act1, a.fO2, a.mbo + 512, act0, residL, w, lane);
  __syncthreads();
  for (int T = w; T < 24; T += 16)
    wprojF(act0, a.fFin, a.finb, a.outF + (size_t)b * 16 * 384, T, lane);
}

// ---------------------------------------------------------------------------
extern "C" void kernel_launch(void* const* d_in, const int* in_sizes, int n_in,
                              void* d_out, int out_size, void* d_ws, size_t ws_size,
                              hipStream_t stream) {
  const float* x    = (const float*)d_in[0];
  const float* adj  = (const float*)d_in[1];
  const float* ginW = (const float*)d_in[2];
  const float* ginb = (const float*)d_in[3];
  const float* geW1 = (const float*)d_in[4];
  const float* geb1 = (const float*)d_in[5];
  const float* geW2 = (const float*)d_in[6];
  const float* geb2 = (const float*)d_in[7];
  const float* gnW1 = (const float*)d_in[8];
  const float* gnb1 = (const float*)d_in[9];
  const float* gnW2 = (const float*)d_in[10];
  const float* gnb2 = (const float*)d_in[11];
  const float* goW  = (const float*)d_in[12];
  const float* gob  = (const float*)d_in[13];
  const float* S    = (const float*)d_in[14];
  const float* mWq  = (const float*)d_in[15];
  const float* mbq  = (const float*)d_in[16];
  const float* mWk  = (const float*)d_in[17];
  const float* mbk  = (const float*)d_in[18];
  const float* mWv  = (const float*)d_in[19];
  const float* mbv  = (const float*)d_in[20];
  const float* mWo  = (const float*)d_in[21];
  const float* mbo  = (const float*)d_in[22];
  const float* finW = (const float*)d_in[23];
  const float* finb = (const float*)d_in[24];
  (void)in_sizes; (void)n_in; (void)out_size; (void)ws_size;

  char* wp = (char*)d_ws;
  size_t off = 0;
  auto alloc = [&](size_t bytes) -> char* {
    char* p = wp + off;
    off += (bytes + 255) & ~(size_t)255;
    return p;
  };
  u16* h_bf     = (u16*)alloc(1024 * 256 * 2);
  float* hWiWjf = (float*)alloc((size_t)1024 * 512 * 4);
  u16* fWiWj    = (u16*)alloc(512 * 256 * 2);
  u16* fW2      = (u16*)alloc(256 * 256 * 2);
  u16* fGn1     = (u16*)alloc(256 * 256 * 2);
  u16* fGn2     = (u16*)alloc(256 * 256 * 2);
  u16* fGo      = (u16*)alloc(256 * 256 * 2);
  u16* fQ0      = (u16*)alloc(256 * 256 * 2);
  u16* fKV0     = (u16*)alloc(512 * 256 * 2);
  u16* fQKV1    = (u16*)alloc(768 * 256 * 2);
  u16* fQKV2    = (u16*)alloc(768 * 256 * 2);
  u16* fO0      = (u16*)alloc(256 * 256 * 2);
  u16* fO1      = (u16*)alloc(256 * 256 * 2);
  u16* fO2      = (u16*)alloc(256 * 256 * 2);
  u16* fFin     = (u16*)alloc(384 * 256 * 2);
  float* bkv0   = (float*)alloc(512 * 4);
  float* bqkv1  = (float*)alloc(768 * 4);
  float* bqkv2  = (float*)alloc(768 * 4);
  u16* q1b      = (u16*)alloc(16 * 256 * 2);
  u16* agg_b    = (u16*)alloc(1024 * 256 * 2);
  u16* kv1      = (u16*)alloc(1024 * 512 * 2);
  float* o1f    = (float*)alloc(64 * 256 * 4);
  u16* o1b      = (u16*)alloc(64 * 256 * 2);

  PreArgs P{};
  int nj = 0, tiles = 0;
  auto addF = [&](const float* s, int stride, u16* d, int nT) {
    P.fsrc[nj] = s; P.fdst[nj] = d; P.fstride[nj] = stride; P.fbase[nj] = tiles;
    tiles += nT; nj++;
  };
  addF(geW1, 256, fWiWj, 16);
  addF(geW1 + 65536, 256, fWiWj + 16 * 4096, 16);
  addF(geW2, 256, fW2, 16);
  addF(gnW1, 256, fGn1, 16);
  addF(gnW2, 256, fGn2, 16);
  addF(goW, 256, fGo, 16);
  addF(mWq, 256, fQ0, 16);
  addF(mWk, 256, fKV0, 16);
  addF(mWv, 256, fKV0 + 16 * 4096, 16);
  addF(mWq + 65536, 256, fQKV1, 16);
  addF(mWk + 65536, 256, fQKV1 + 16 * 4096, 16);
  addF(mWv + 65536, 256, fQKV1 + 32 * 4096, 16);
  addF(mWq + 131072, 256, fQKV2, 16);
  addF(mWk + 131072, 256, fQKV2 + 16 * 4096, 16);
  addF(mWv + 131072, 256, fQKV2 + 32 * 4096, 16);
  addF(mWo, 256, fO0, 16);
  addF(mWo + 65536, 256, fO1, 16);
  addF(mWo + 131072, 256, fO2, 16);
  addF(finW, 384, fFin, 24);
  P.fbase[nj] = tiles;
  P.fragTiles = tiles;
  P.hBase = tiles;
  P.prepBid = tiles + 256;
  P.q1Bid = tiles + 257;
  P.x = x; P.ginW = ginW; P.ginb = ginb; P.h_bf = h_bf;
  P.mbk = mbk; P.mbv = mbv; P.mbq = mbq; P.S = S; P.mWq = mWq;
  P.bkv0 = bkv0; P.bqkv1 = bqkv1; P.bqkv2 = bqkv2; P.q1b = q1b;

  TailArgs T{};
  T.agg = agg_b; T.fGn1 = fGn1; T.fGn2 = fGn2; T.fGo = fGo; T.fKV0 = fKV0;
  T.fQKV1 = fQKV1; T.fQKV2 = fQKV2; T.fO0 = fO0; T.fO1 = fO1; T.fO2 = fO2;
  T.fFin = fFin; T.q1b = q1b;
  T.gnb1 = gnb1; T.gnb2 = gnb2; T.gob = gob;
  T.bkv0 = bkv0; T.bqkv1 = bqkv1; T.bqkv2 = bqkv2; T.mbo = mbo; T.finb = finb;
  T.kv1 = kv1; T.o1b = o1b; T.o1f = o1f; T.outF = (float*)d_out;

  k_pre<<<dim3(tiles + 258), dim3(256), 0, stream>>>(P);
  k_wiwj<<<dim3(16, 4), dim3(256), 0, stream>>>(h_bf, fWiWj, hWiWjf);
  k_edge<<<dim3(1024), dim3(256), 0, stream>>>(hWiWjf, adj, geb1, fW2, geb2, agg_b);
  k_tail<<<dim3(4), dim3(1024), 0, stream>>>(T);
}

// Round 10
// 306.684 us; speedup vs baseline: 1.6964x; 1.6964x over previous
//
#include <hip/hip_runtime.h>
#include <hip/hip_bf16.h>

typedef unsigned short u16;
typedef __bf16 bf8v __attribute__((ext_vector_type(8)));
typedef float f4v __attribute__((ext_vector_type(4)));

__device__ __forceinline__ float b2f(u16 v) {
  union { unsigned u; float f; } x; x.u = ((unsigned)v) << 16; return x.f;
}
__device__ __forceinline__ u16 f2b(float f) {
  union { float f; unsigned u; } x; x.f = f;
  unsigned r = (x.u + 0x7FFFu + ((x.u >> 16) & 1u)) >> 16;
  return (u16)r;
}
__device__ __forceinline__ unsigned pkbf(float a, float b) {
  union { __hip_bfloat162 h; unsigned u; } c;
  c.h = __float22bfloat162_rn(make_float2(a, b));
  return c.u;
}
__device__ __forceinline__ void up2(unsigned u, float& lo, float& hi) {
  union { unsigned x; float f; } a, b;
  a.x = u << 16; b.x = u & 0xffff0000u; lo = a.f; hi = b.f;
}

// ---------------------------------------------------------------------------
// Fragment-major weight layout: for weight W[k=0..255][n], tile T=n>>4:
// frag[((T*8+kt)*64+lane)*8 + j] = bf16(W[kt*32+(lane>>4)*8+j][T*16+(lane&15)])
// ---------------------------------------------------------------------------
#define NFRAG 19
struct PreArgs {
  const float* fsrc[NFRAG];
  u16* fdst[NFRAG];
  int fstride[NFRAG];
  int fbase[NFRAG + 1];
  int fragTiles, hBase, prepBid, q1Bid;
  const float *x, *ginW, *ginb;
  u16* h_bf;
  const float *mbk, *mbv, *mbq, *S, *mWq;
  float *bkv0, *bqkv1, *bqkv2;
  u16* q1b;
};

__global__ __launch_bounds__(256) void k_pre(PreArgs a) {
  __shared__ u16 ld[256 * 20];
  __shared__ float xs[4][48];
  __shared__ float Ss[4096];
  const int bid = blockIdx.x, t = threadIdx.x;

  if (bid < a.fragTiles) {
    int j = 0;
    while (j + 1 < NFRAG && a.fbase[j + 1] <= bid) j++;
    const int localT = bid - a.fbase[j];
    const float* src = a.fsrc[j];
    const int Ns = a.fstride[j];
    const int n0 = localT * 16;
    {
      const float* s = src + (size_t)t * Ns + n0;
      const float4 v0 = ((const float4*)s)[0], v1 = ((const float4*)s)[1];
      const float4 v2 = ((const float4*)s)[2], v3 = ((const float4*)s)[3];
      unsigned* row = (unsigned*)(ld + t * 20);
      row[0] = pkbf(v0.x, v0.y); row[1] = pkbf(v0.z, v0.w);
      row[2] = pkbf(v1.x, v1.y); row[3] = pkbf(v1.z, v1.w);
      row[4] = pkbf(v2.x, v2.y); row[5] = pkbf(v2.z, v2.w);
      row[6] = pkbf(v3.x, v3.y); row[7] = pkbf(v3.z, v3.w);
    }
    __syncthreads();
    u16* dst = a.fdst[j] + (size_t)localT * 4096;
#pragma unroll
    for (int s2 = 0; s2 < 2; s2++) {
      const int o = t * 2 + s2, kt = o >> 6, lane = o & 63;
      const int nlo = lane & 15, bk = kt * 32 + ((lane >> 4) << 3);
      union { u16 h[8]; uint4 q; } pk;
#pragma unroll
      for (int j2 = 0; j2 < 8; j2++) pk.h[j2] = ld[(bk + j2) * 20 + nlo];
      *(uint4*)(dst + (size_t)(kt * 64 + lane) * 8) = pk.q;
    }
    return;
  }
  if (bid >= a.hBase && bid < a.hBase + 256) {
    const int row0 = (bid - a.hBase) * 4;
    if (t < 192) {
      const int rr = t / 48, k = t % 48;
      xs[rr][k] = a.x[(size_t)(row0 + rr) * 48 + k];
    }
    __syncthreads();
    const float bias = a.ginb[t];
    float acc[4] = {bias, bias, bias, bias};
    for (int k = 0; k < 48; k++) {
      const float w = a.ginW[(size_t)k * 256 + t];
#pragma unroll
      for (int rr = 0; rr < 4; rr++) acc[rr] += xs[rr][k] * w;
    }
#pragma unroll
    for (int rr = 0; rr < 4; rr++) a.h_bf[(size_t)(row0 + rr) * 256 + t] = f2b(acc[rr]);
    return;
  }
  if (bid == a.prepBid) {
    a.bkv0[t] = a.mbk[t]; a.bkv0[256 + t] = a.mbv[t];
    a.bqkv1[t] = a.mbq[256 + t]; a.bqkv1[256 + t] = a.mbk[256 + t]; a.bqkv1[512 + t] = a.mbv[256 + t];
    a.bqkv2[t] = a.mbq[512 + t]; a.bqkv2[256 + t] = a.mbk[512 + t]; a.bqkv2[512 + t] = a.mbv[512 + t];
    return;
  }
  if (bid == a.q1Bid) {
    for (int idx = t; idx < 4096; idx += 256) Ss[idx] = a.S[idx];
    __syncthreads();
    float acc[16];
#pragma unroll
    for (int r = 0; r < 16; r++) acc[r] = 0.f;
    for (int k = 0; k < 256; k++) {
      const float w = a.mWq[(size_t)k * 256 + t];
#pragma unroll
      for (int r = 0; r < 16; r++) acc[r] += Ss[r * 256 + k] * w;
    }
    const float bq = a.mbq[t];
#pragma unroll
    for (int r = 0; r < 16; r++) a.q1b[r * 256 + t] = f2b(acc[r] + bq);
    return;
  }
}

// ---------------------------------------------------------------------------
// hWiWj GEMM
// ---------------------------------------------------------------------------
__global__ __launch_bounds__(256) void k_wiwj(
    const u16* __restrict__ h, const u16* __restrict__ frag, float* __restrict__ out) {
  __shared__ __align__(16) u16 As[64 * 264];
  const int t = threadIdx.x, lane = t & 63, wv = t >> 6;
  const int m0 = blockIdx.x * 64, n0 = blockIdx.y * 128;
  {
    const int row = t >> 2, ch = t & 3;
#pragma unroll
    for (int s = 0; s < 8; s++)
      *(uint4*)(As + row * 264 + ch * 64 + s * 8) =
          *(const uint4*)(h + (size_t)(m0 + row) * 256 + ch * 64 + s * 8);
  }
  __syncthreads();
  f4v acc[4][2];
#pragma unroll
  for (int mt = 0; mt < 4; mt++)
#pragma unroll
    for (int nt = 0; nt < 2; nt++) acc[mt][nt] = (f4v){0.f, 0.f, 0.f, 0.f};
  const int Tw = (n0 >> 4) + wv * 2;
#pragma unroll
  for (int kt = 0; kt < 8; kt++) {
    bf8v af[4], bf[2];
#pragma unroll
    for (int mt = 0; mt < 4; mt++)
      af[mt] = *(const bf8v*)(As + (mt * 16 + (lane & 15)) * 264 + kt * 32 + ((lane >> 4) << 3));
#pragma unroll
    for (int nt = 0; nt < 2; nt++)
      bf[nt] = *(const bf8v*)(frag + ((size_t)((Tw + nt) * 8 + kt) * 64 + lane) * 8);
#pragma unroll
    for (int mt = 0; mt < 4; mt++)
#pragma unroll
      for (int nt = 0; nt < 2; nt++)
        acc[mt][nt] = __builtin_amdgcn_mfma_f32_16x16x32_bf16(af[mt], bf[nt], acc[mt][nt], 0, 0, 0);
  }
#pragma unroll
  for (int mt = 0; mt < 4; mt++)
#pragma unroll
    for (int nt = 0; nt < 2; nt++) {
      const int n = n0 + wv * 32 + nt * 16 + (lane & 15);
      const int mb = m0 + mt * 16 + ((lane >> 4) << 2);
#pragma unroll
      for (int r = 0; r < 4; r++) out[(size_t)(mb + r) * 512 + n] = acc[mt][nt][r];
    }
}

// ---------------------------------------------------------------------------
// Edge MLP + masked aggregation. 3 blocks/CU for latency hiding.
// ---------------------------------------------------------------------------
__global__ __launch_bounds__(256, 3) void k_edge(
    const float* __restrict__ hWiWj, const float* __restrict__ adj,
    const float* __restrict__ geb1, const u16* __restrict__ fragW2,
    const float* __restrict__ geb2, u16* __restrict__ aggB) {
  __shared__ __align__(16) u16 As[64 * 264];
  __shared__ float hi[256];
  __shared__ int jlist[256];
  __shared__ int cnt;
  const int t = threadIdx.x, lane = t & 63, wv = t >> 6;
  const int b = blockIdx.x >> 8, i = blockIdx.x & 255;
  if (t == 0) cnt = 0;
  __syncthreads();
  {
    const float a = adj[(size_t)(b * 256 + i) * 256 + t];
    hi[t] = hWiWj[(size_t)(b * 256 + i) * 512 + t] + geb1[t];
    if (a != 0.f) { const int p = atomicAdd(&cnt, 1); jlist[p] = t; }
  }
  __syncthreads();
  const int nact = cnt;
  if (nact == 0) {
    if (lane < 16) {
#pragma unroll
      for (int nt = 0; nt < 4; nt++)
        aggB[(size_t)(b * 256 + i) * 256 + wv * 64 + nt * 16 + lane] = 0;
    }
    return;
  }
  const int nch = (nact + 63) >> 6;
  float bias2[4];
#pragma unroll
  for (int nt = 0; nt < 4; nt++) bias2[nt] = geb2[wv * 64 + nt * 16 + (lane & 15)];
  float aggAcc[4] = {0.f, 0.f, 0.f, 0.f};
  const u16* fw = fragW2 + lane * 8;

  for (int c = 0; c < nch; c++) {
    const int rows = min(64, nact - c * 64);
    {
      const int r = t >> 2, q = t & 3;
      const bool valid = (r < rows);
      const int j = valid ? jlist[c * 64 + r] : jlist[0];
      const float4* s4 = (const float4*)(hWiWj + (size_t)(b * 256 + j) * 512 + 256 + q * 64);
      u16* dstrow = As + r * 264 + q * 64;
#pragma unroll
      for (int ii = 0; ii < 8; ii++) {
        const float4 v0 = s4[ii * 2];
        const float4 v1 = s4[ii * 2 + 1];
        const int k = q * 64 + ii * 8;
        uint4 qd;
        qd.x = pkbf(fmaxf(v0.x + hi[k + 0], 0.f), fmaxf(v0.y + hi[k + 1], 0.f));
        qd.y = pkbf(fmaxf(v0.z + hi[k + 2], 0.f), fmaxf(v0.w + hi[k + 3], 0.f));
        qd.z = pkbf(fmaxf(v1.x + hi[k + 4], 0.f), fmaxf(v1.y + hi[k + 5], 0.f));
        qd.w = pkbf(fmaxf(v1.z + hi[k + 6], 0.f), fmaxf(v1.w + hi[k + 7], 0.f));
        *(uint4*)(dstrow + ii * 8) = qd;
      }
    }
    __syncthreads();
    f4v acc[4][4];
#pragma unroll
    for (int jt = 0; jt < 4; jt++)
#pragma unroll
      for (int nt = 0; nt < 4; nt++) acc[jt][nt] = (f4v){0.f, 0.f, 0.f, 0.f};
    bf8v bcur[4];
#pragma unroll
    for (int nt = 0; nt < 4; nt++)
      bcur[nt] = *(const bf8v*)(fw + (size_t)((wv * 4 + nt) * 8 + 0) * 512);
#pragma unroll
    for (int kt = 0; kt < 8; kt++) {
      bf8v bnxt[4];
      if (kt < 7) {
#pragma unroll
        for (int nt = 0; nt < 4; nt++)
          bnxt[nt] = *(const bf8v*)(fw + (size_t)((wv * 4 + nt) * 8 + kt + 1) * 512);
      }
      bf8v af[4];
#pragma unroll
      for (int jt = 0; jt < 4; jt++)
        af[jt] = *(const bf8v*)(As + (jt * 16 + (lane & 15)) * 264 + kt * 32 + ((lane >> 4) << 3));
#pragma unroll
      for (int nt = 0; nt < 4; nt++)
#pragma unroll
        for (int jt = 0; jt < 4; jt++)
          acc[jt][nt] = __builtin_amdgcn_mfma_f32_16x16x32_bf16(af[jt], bcur[nt], acc[jt][nt], 0, 0, 0);
      if (kt < 7) {
#pragma unroll
        for (int nt = 0; nt < 4; nt++) bcur[nt] = bnxt[nt];
      }
    }
    const int rbase = (lane >> 4) * 4;
#pragma unroll
    for (int nt = 0; nt < 4; nt++) {
      float s = 0.f;
#pragma unroll
      for (int jt = 0; jt < 4; jt++) {
        const int r0 = jt * 16 + rbase;
#pragma unroll
        for (int r = 0; r < 4; r++) {
          const float e = fmaxf(acc[jt][nt][r] + bias2[nt], 0.f);
          s += (r0 + r < rows) ? e : 0.f;
        }
      }
      s += __shfl_xor(s, 16);
      s += __shfl_xor(s, 32);
      aggAcc[nt] += s;
    }
    __syncthreads();
  }
  if (lane < 16) {
#pragma unroll
    for (int nt = 0; nt < 4; nt++) {
      const int n = wv * 64 + nt * 16 + lane;
      aggB[(size_t)(b * 256 + i) * 256 + n] = f2b(aggAcc[nt]);
    }
  }
}

// ---------------------------------------------------------------------------
// Fused tail v4: 32 blocks x 256 threads. Phases 1-2 = round-8 structure
// (2 grid barriers); phase 3 = in-LDS per-b chain on blocks 0-3 (256 threads,
// no spill, no barriers).
// ---------------------------------------------------------------------------
#define NBLK 32

__device__ __forceinline__ void gridbar(int* cnt, int gen) {
  __syncthreads();
  if (threadIdx.x == 0) {
    __threadfence();
    __hip_atomic_fetch_add(cnt, 1, __ATOMIC_RELAXED, __HIP_MEMORY_SCOPE_AGENT);
    int it = 0;
    while (__hip_atomic_load(cnt, __ATOMIC_RELAXED, __HIP_MEMORY_SCOPE_AGENT) < NBLK * gen) {
      __builtin_amdgcn_s_sleep(8);
      if (((++it) & 255) == 0)
        __hip_atomic_fetch_add(cnt, 0, __ATOMIC_RELAXED, __HIP_MEMORY_SCOPE_AGENT);
    }
    __threadfence();
  }
  __syncthreads();
}

// M=32 GEMM, A in LDS (stride 264), frag-major B, out LDS bf16 (stride 264)
__device__ void g32(const u16* Al, const u16* frag, const float* bias, int relu,
                    u16* Ol, int t) {
  const int lane = t & 63, wv = t >> 6;
  f4v acc[2][4];
#pragma unroll
  for (int mt = 0; mt < 2; mt++)
#pragma unroll
    for (int nt = 0; nt < 4; nt++) acc[mt][nt] = (f4v){0.f, 0.f, 0.f, 0.f};
#pragma unroll
  for (int kt = 0; kt < 8; kt++) {
    bf8v af[2], bf[4];
#pragma unroll
    for (int mt = 0; mt < 2; mt++)
      af[mt] = *(const bf8v*)(Al + (mt * 16 + (lane & 15)) * 264 + kt * 32 + ((lane >> 4) << 3));
#pragma unroll
    for (int nt = 0; nt < 4; nt++)
      bf[nt] = *(const bf8v*)(frag + ((size_t)((wv * 4 + nt) * 8 + kt) * 64 + lane) * 8);
#pragma unroll
    for (int mt = 0; mt < 2; mt++)
#pragma unroll
      for (int nt = 0; nt < 4; nt++)
        acc[mt][nt] = __builtin_amdgcn_mfma_f32_16x16x32_bf16(af[mt], bf[nt], acc[mt][nt], 0, 0, 0);
  }
#pragma unroll
  for (int mt = 0; mt < 2; mt++)
#pragma unroll
    for (int nt = 0; nt < 4; nt++) {
      const int col = wv * 64 + nt * 16 + (lane & 15);
      const float bv = bias[col];
#pragma unroll
      for (int r = 0; r < 4; r++) {
        const int row = mt * 16 + ((lane >> 4) << 2) + r;
        float v = acc[mt][nt][r] + bv;
        if (relu) v = fmaxf(v, 0.f);
        Ol[row * 264 + col] = f2b(v);
      }
    }
}

// M=32, N=512 GEMM -> global bf16 (kv1)
__device__ void g32kv(const u16* Al, const u16* frag, const float* bias,
                      u16* outG, int t) {
  const int lane = t & 63, wv = t >> 6;
  f4v acc[2][8];
#pragma unroll
  for (int mt = 0; mt < 2; mt++)
#pragma unroll
    for (int nt = 0; nt < 8; nt++) acc[mt][nt] = (f4v){0.f, 0.f, 0.f, 0.f};
#pragma unroll
  for (int kt = 0; kt < 8; kt++) {
    bf8v af[2];
#pragma unroll
    for (int mt = 0; mt < 2; mt++)
      af[mt] = *(const bf8v*)(Al + (mt * 16 + (lane & 15)) * 264 + kt * 32 + ((lane >> 4) << 3));
#pragma unroll
    for (int nt = 0; nt < 8; nt++) {
      const bf8v bf = *(const bf8v*)(frag + ((size_t)((wv * 8 + nt) * 8 + kt) * 64 + lane) * 8);
#pragma unroll
      for (int mt = 0; mt < 2; mt++)
        acc[mt][nt] = __builtin_amdgcn_mfma_f32_16x16x32_bf16(af[mt], bf, acc[mt][nt], 0, 0, 0);
    }
  }
#pragma unroll
  for (int mt = 0; mt < 2; mt++)
#pragma unroll
    for (int nt = 0; nt < 8; nt++) {
      const int col = wv * 128 + nt * 16 + (lane & 15);
      const float bv = bias[col];
#pragma unroll
      for (int r = 0; r < 4; r++) {
        const int row = mt * 16 + ((lane >> 4) << 2) + r;
        outG[(size_t)row * 512 + col] = f2b(acc[mt][nt][r] + bv);
      }
    }
}

// attn1 (Lk=256), one (b,hd) per block, vectorized loads.
__device__ void attn_tile(const u16* __restrict__ qbuf,
                          const u16* __restrict__ kbuf, const u16* __restrict__ vbuf,
                          float* __restrict__ oF, u16* __restrict__ oB,
                          int b, int hd, float* qs, float* sc, float* vs, int t) {
  const int lane = t & 63, wv = t >> 6;
  const int Lk = 256;
  if (t < 64) {
    const int row = t >> 2, part = t & 3;
    const uint4 q4 = *(const uint4*)(qbuf + (size_t)row * 256 + hd * 32 + part * 8);
    float f0, f1, f2, f3, f4, f5, f6, f7;
    up2(q4.x, f0, f1); up2(q4.y, f2, f3); up2(q4.z, f4, f5); up2(q4.w, f6, f7);
    float4* d = (float4*)(qs + row * 32 + part * 8);
    d[0] = make_float4(f0, f1, f2, f3);
    d[1] = make_float4(f4, f5, f6, f7);
  }
  __syncthreads();
  {
    float kv[32];
    const uint4* kp = (const uint4*)(kbuf + (size_t)(b * Lk + t) * 512 + hd * 32);
#pragma unroll
    for (int c4 = 0; c4 < 4; c4++) {
      const uint4 k4 = kp[c4];
      up2(k4.x, kv[c4 * 8 + 0], kv[c4 * 8 + 1]);
      up2(k4.y, kv[c4 * 8 + 2], kv[c4 * 8 + 3]);
      up2(k4.z, kv[c4 * 8 + 4], kv[c4 * 8 + 5]);
      up2(k4.w, kv[c4 * 8 + 6], kv[c4 * 8 + 7]);
    }
    for (int r = 0; r < 16; r++) {
      float s = 0.f;
#pragma unroll
      for (int d = 0; d < 32; d++) s += qs[r * 32 + d] * kv[d];
      sc[r * 256 + t] = s * 0.0625f;
    }
  }
  __syncthreads();
  for (int r = wv * 4; r < wv * 4 + 4; r++) {
    float v[4];
    float mx = -1e30f;
#pragma unroll
    for (int q2 = 0; q2 < 4; q2++) {
      v[q2] = sc[r * 256 + lane + q2 * 64];
      mx = fmaxf(mx, v[q2]);
    }
    for (int off = 32; off; off >>= 1) mx = fmaxf(mx, __shfl_xor(mx, off));
    float sum = 0.f;
#pragma unroll
    for (int q2 = 0; q2 < 4; q2++) { v[q2] = __expf(v[q2] - mx); sum += v[q2]; }
    for (int off = 32; off; off >>= 1) sum += __shfl_xor(sum, off);
    const float inv = 1.f / sum;
#pragma unroll
    for (int q2 = 0; q2 < 4; q2++) sc[r * 256 + lane + q2 * 64] = v[q2] * inv;
  }
  __syncthreads();
  for (int u = t; u < 1024; u += 256) {
    const int row = u >> 2, part = u & 3;
    const uint4 v4 = *(const uint4*)(vbuf + (size_t)(b * Lk + row) * 512 + hd * 32 + part * 8);
    float f0, f1, f2, f3, f4, f5, f6, f7;
    up2(v4.x, f0, f1); up2(v4.y, f2, f3); up2(v4.z, f4, f5); up2(v4.w, f6, f7);
    float4* d = (float4*)(vs + row * 32 + part * 8);
    d[0] = make_float4(f0, f1, f2, f3);
    d[1] = make_float4(f4, f5, f6, f7);
  }
  __syncthreads();
  const int r0 = t >> 5, d = t & 31;
  float a0 = qs[r0 * 32 + d], a1 = qs[(r0 + 8) * 32 + d];
#pragma unroll 4
  for (int j = 0; j < Lk; j++) {
    const float vv = vs[j * 32 + d];
    a0 += sc[r0 * 256 + j] * vv;
    a1 += sc[(r0 + 8) * 256 + j] * vv;
  }
  const int c0 = hd * 32 + d;
  oF[(size_t)(b * 16 + r0) * 256 + c0] = a0;
  oB[(size_t)(b * 16 + r0) * 256 + c0] = f2b(a0);
  oF[(size_t)(b * 16 + r0 + 8) * 256 + c0] = a1;
  oB[(size_t)(b * 16 + r0 + 8) * 256 + c0] = f2b(a1);
}

// ---- phase-3 wave units (verified in round 9) ----
__device__ void wprojG(const u16* __restrict__ o1b, const float* __restrict__ o1f,
                       const u16* __restrict__ frag, const float* __restrict__ bias,
                       u16* actL, float* residL, int b, int T, int lane) {
  f4v acc = (f4v){0.f, 0.f, 0.f, 0.f};
  const u16* abase = o1b + (size_t)(b * 16 + (lane & 15)) * 256 + ((lane >> 4) << 3);
  const u16* fbase = frag + ((size_t)(T * 8) * 64 + lane) * 8;
#pragma unroll
  for (int kt = 0; kt < 8; kt++)
    acc = __builtin_amdgcn_mfma_f32_16x16x32_bf16(*(const bf8v*)(abase + kt * 32),
                                                  *(const bf8v*)(fbase + (size_t)kt * 512), acc, 0, 0, 0);
  const int col = T * 16 + (lane & 15);
  const float bv = bias[col];
#pragma unroll
  for (int r = 0; r < 4; r++) {
    const int row = ((lane >> 4) << 2) + r;
    const float v = fmaxf(acc[r] + bv, 0.f) + o1f[(size_t)(b * 16 + row) * 256 + col];
    residL[row * 256 + col] = v;
    actL[row * 264 + col] = f2b(v);
  }
}

__device__ void wprojQ(const u16* actL, const u16* __restrict__ frag,
                       const float* __restrict__ bias, u16* qkvL, int T, int lane) {
  f4v acc = (f4v){0.f, 0.f, 0.f, 0.f};
  const u16* abase = actL + (lane & 15) * 264 + ((lane >> 4) << 3);
  const u16* fbase = frag + ((size_t)(T * 8) * 64 + lane) * 8;
#pragma unroll
  for (int kt = 0; kt < 8; kt++)
    acc = __builtin_amdgcn_mfma_f32_16x16x32_bf16(*(const bf8v*)(abase + kt * 32),
                                                  *(const bf8v*)(fbase + (size_t)kt * 512), acc, 0, 0, 0);
  const int col = T * 16 + (lane & 15);
  const float bv = bias[col];
#pragma unroll
  for (int r = 0; r < 4; r++) {
    const int row = ((lane >> 4) << 2) + r;
    qkvL[row * 776 + col] = f2b(acc[r] + bv);
  }
}

__device__ void wprojR(const u16* actIn, const u16* __restrict__ frag,
                       const float* __restrict__ bias, u16* actOut, float* residL,
                       int T, int lane) {
  f4v acc = (f4v){0.f, 0.f, 0.f, 0.f};
  const u16* abase = actIn + (lane & 15) * 264 + ((lane >> 4) << 3);
  const u16* fbase = frag + ((size_t)(T * 8) * 64 + lane) * 8;
#pragma unroll
  for (int kt = 0; kt < 8; kt++)
    acc = __builtin_amdgcn_mfma_f32_16x16x32_bf16(*(const bf8v*)(abase + kt * 32),
                                                  *(const bf8v*)(fbase + (size_t)kt * 512), acc, 0, 0, 0);
  const int col = T * 16 + (lane & 15);
  const float bv = bias[col];
#pragma unroll
  for (int r = 0; r < 4; r++) {
    const int row = ((lane >> 4) << 2) + r;
    const float v = fmaxf(acc[r] + bv, 0.f) + residL[row * 256 + col];
    residL[row * 256 + col] = v;
    actOut[row * 264 + col] = f2b(v);
  }
}

__device__ void wprojF(const u16* actL, const u16* __restrict__ frag,
                       const float* __restrict__ bias, float* __restrict__ outG,
                       int T, int lane) {
  f4v acc = (f4v){0.f, 0.f, 0.f, 0.f};
  const u16* abase = actL + (lane & 15) * 264 + ((lane >> 4) << 3);
  const u16* fbase = frag + ((size_t)(T * 8) * 64 + lane) * 8;
#pragma unroll
  for (int kt = 0; kt < 8; kt++)
    acc = __builtin_amdgcn_mfma_f32_16x16x32_bf16(*(const bf8v*)(abase + kt * 32),
                                                  *(const bf8v*)(fbase + (size_t)kt * 512), acc, 0, 0, 0);
  const int col = T * 16 + (lane & 15);
  const float bv = bias[col];
#pragma unroll
  for (int r = 0; r < 4; r++) {
    const int row = ((lane >> 4) << 2) + r;
    outG[(size_t)row * 384 + col] = acc[r] + bv;
  }
}

// In-LDS attention (Lk=16), one head per call, per-wave scratch ps.
__device__ void attnB(const u16* qkvL, float* residL, u16* actOut, float* ps,
                      int hd, int lane) {
  const int r = lane & 15, cg = lane >> 4;
  float qv[32];
  {
    const uint4* qp = (const uint4*)(qkvL + r * 776 + hd * 32);
#pragma unroll
    for (int c4 = 0; c4 < 4; c4++) {
      const uint4 q4 = qp[c4];
      up2(q4.x, qv[c4 * 8 + 0], qv[c4 * 8 + 1]);
      up2(q4.y, qv[c4 * 8 + 2], qv[c4 * 8 + 3]);
      up2(q4.z, qv[c4 * 8 + 4], qv[c4 * 8 + 5]);
      up2(q4.w, qv[c4 * 8 + 6], qv[c4 * 8 + 7]);
    }
  }
  float p[4];
#pragma unroll
  for (int c = 0; c < 4; c++) {
    const int cc = cg * 4 + c;
    const uint4* kp = (const uint4*)(qkvL + cc * 776 + 256 + hd * 32);
    float s = 0.f;
#pragma unroll
    for (int c4 = 0; c4 < 4; c4++) {
      const uint4 k4 = kp[c4];
      float k0, k1;
      up2(k4.x, k0, k1); s += qv[c4 * 8 + 0] * k0 + qv[c4 * 8 + 1] * k1;
      up2(k4.y, k0, k1); s += qv[c4 * 8 + 2] * k0 + qv[c4 * 8 + 3] * k1;
      up2(k4.z, k0, k1); s += qv[c4 * 8 + 4] * k0 + qv[c4 * 8 + 5] * k1;
      up2(k4.w, k0, k1); s += qv[c4 * 8 + 6] * k0 + qv[c4 * 8 + 7] * k1;
    }
    p[c] = s * 0.0625f;
  }
  float mx = fmaxf(fmaxf(p[0], p[1]), fmaxf(p[2], p[3]));
  mx = fmaxf(mx, __shfl_xor(mx, 16));
  mx = fmaxf(mx, __shfl_xor(mx, 32));
  float sum = 0.f;
#pragma unroll
  for (int c = 0; c < 4; c++) { p[c] = __expf(p[c] - mx); sum += p[c]; }
  sum += __shfl_xor(sum, 16);
  sum += __shfl_xor(sum, 32);
  const float inv = 1.f / sum;
#pragma unroll
  for (int c = 0; c < 4; c++) ps[r * 16 + cg * 4 + c] = p[c] * inv;
  float o[8];
#pragma unroll
  for (int j = 0; j < 8; j++) o[j] = qv[cg * 8 + j];
#pragma unroll
  for (int c = 0; c < 16; c++) {
    const float pv = ps[r * 16 + c];
    const uint4 v4 = *(const uint4*)(qkvL + c * 776 + 512 + hd * 32 + cg * 8);
    float v0, v1;
    up2(v4.x, v0, v1); o[0] += pv * v0; o[1] += pv * v1;
    up2(v4.y, v0, v1); o[2] += pv * v0; o[3] += pv * v1;
    up2(v4.z, v0, v1); o[4] += pv * v0; o[5] += pv * v1;
    up2(v4.w, v0, v1); o[6] += pv * v0; o[7] += pv * v1;
  }
  const int col0 = hd * 32 + cg * 8;
#pragma unroll
  for (int j = 0; j < 8; j++) residL[r * 256 + col0 + j] = o[j];
  unsigned* ob = (unsigned*)(actOut + r * 264 + col0);
  ob[0] = pkbf(o[0], o[1]); ob[1] = pkbf(o[2], o[3]);
  ob[2] = pkbf(o[4], o[5]); ob[3] = pkbf(o[6], o[7]);
}

struct TailArgs {
  const u16 *agg, *fGn1, *fGn2, *fGo, *fKV0, *fQKV1, *fQKV2, *fO0, *fO1, *fO2, *fFin, *q1b;
  const float *gnb1, *gnb2, *gob, *bkv0, *bqkv1, *bqkv2, *mbo, *finb;
  u16 *kv1, *o1b;
  float *o1f, *outF;
  int* bar;
};

__global__ __launch_bounds__(256) void k_tail(TailArgs a) {
  __shared__ __align__(16) char smem[62208];
  const int bid = blockIdx.x, t = threadIdx.x;
  const int lane = t & 63, w = t >> 6;

  {  // ---- phase 1: rows bid*32..+31: agg -> n1 -> n2 -> enc -> kv1 ----
    u16* actA = (u16*)smem;
    u16* actB = (u16*)(smem + 16896);
    const int r0 = bid * 32;
#pragma unroll
    for (int s = 0; s < 4; s++) {
      const int u = t * 4 + s, row = u >> 5, ch = u & 31;
      *(uint4*)(actA + row * 264 + ch * 8) =
          *(const uint4*)(a.agg + (size_t)(r0 + row) * 256 + ch * 8);
    }
    __syncthreads();
    g32(actA, a.fGn1, a.gnb1, 1, actB, t); __syncthreads();
    g32(actB, a.fGn2, a.gnb2, 1, actA, t); __syncthreads();
    g32(actA, a.fGo, a.gob, 0, actB, t); __syncthreads();
    g32kv(actB, a.fKV0, a.bkv0, a.kv1 + (size_t)r0 * 512, t);
  }
  gridbar(a.bar, 1);
  {  // ---- phase 2: attn1, one (b,hd) per block ----
    float* qs = (float*)smem;
    float* sc = (float*)(smem + 2048);
    float* vs = (float*)(smem + 18432);
    attn_tile(a.q1b, a.kv1, a.kv1 + 256, a.o1f, a.o1b, bid >> 3, bid & 7, qs, sc, vs, t);
  }
  gridbar(a.bar, 2);
  if (bid >= 4) return;
  {  // ---- phase 3: block b: mab2 + mab3 + final, all in LDS, 4 waves ----
    const int b = bid;
    u16* act0 = (u16*)smem;                 // 8448
    u16* act1 = (u16*)(smem + 8448);        // 8448
    u16* qkvL = (u16*)(smem + 16896);       // 24832
    float* residL = (float*)(smem + 41728); // 16384
    float* psL = (float*)(smem + 58112);    // 4096
    __syncthreads();
    for (int T = w; T < 16; T += 4) wprojG(a.o1b, a.o1f, a.fO0, a.mbo, act0, residL, b, T, lane);
    __syncthreads();
    for (int T = w; T < 48; T += 4) wprojQ(act0, a.fQKV1, a.bqkv1, qkvL, T, lane);
    __syncthreads();
    for (int hd = w; hd < 8; hd += 4) attnB(qkvL, residL, act1, psL + w * 256, hd, lane);
    __syncthreads();
    for (int T = w; T < 16; T += 4) wprojR(act1, a.fO1, a.mbo + 256, act0, residL, T, lane);
    __syncthreads();
    for (int T = w; T < 48; T += 4) wprojQ(act0, a.fQKV2, a.bqkv2, qkvL, T, lane);
    __syncthreads();
    for (int hd = w; hd < 8; hd += 4) attnB(qkvL, residL, act1, psL + w * 256, hd, lane);
    __syncthreads();
    for (int T = w; T < 16; T += 4) wprojR(act1, a.fO2, a.mbo + 512, act0, residL, T, lane);
    __syncthreads();
    for (int T = w; T < 24; T += 4)
      wprojF(act0, a.fFin, a.finb, a.outF + (size_t)b * 16 * 384, T, lane);
  }
}

// ---------------------------------------------------------------------------
extern "C" void kernel_launch(void* const* d_in, const int* in_sizes, int n_in,
                              void* d_out, int out_size, void* d_ws, size_t ws_size,
                              hipStream_t stream) {
  const float* x    = (const float*)d_in[0];
  const float* adj  = (const float*)d_in[1];
  const float* ginW = (const float*)d_in[2];
  const float* ginb = (const float*)d_in[3];
  const float* geW1 = (const float*)d_in[4];
  const float* geb1 = (const float*)d_in[5];
  const float* geW2 = (const float*)d_in[6];
  const float* geb2 = (const float*)d_in[7];
  const float* gnW1 = (const float*)d_in[8];
  const float* gnb1 = (const float*)d_in[9];
  const float* gnW2 = (const float*)d_in[10];
  const float* gnb2 = (const float*)d_in[11];
  const float* goW  = (const float*)d_in[12];
  const float* gob  = (const float*)d_in[13];
  const float* S    = (const float*)d_in[14];
  const float* mWq  = (const float*)d_in[15];
  const float* mbq  = (const float*)d_in[16];
  const float* mWk  = (const float*)d_in[17];
  const float* mbk  = (const float*)d_in[18];
  const float* mWv  = (const float*)d_in[19];
  const float* mbv  = (const float*)d_in[20];
  const float* mWo  = (const float*)d_in[21];
  const float* mbo  = (const float*)d_in[22];
  const float* finW = (const float*)d_in[23];
  const float* finb = (const float*)d_in[24];
  (void)in_sizes; (void)n_in; (void)out_size; (void)ws_size;

  char* wp = (char*)d_ws;
  size_t off = 0;
  auto alloc = [&](size_t bytes) -> char* {
    char* p = wp + off;
    off += (bytes + 255) & ~(size_t)255;
    return p;
  };
  u16* h_bf     = (u16*)alloc(1024 * 256 * 2);
  float* hWiWjf = (float*)alloc((size_t)1024 * 512 * 4);
  u16* fWiWj    = (u16*)alloc(512 * 256 * 2);
  u16* fW2      = (u16*)alloc(256 * 256 * 2);
  u16* fGn1     = (u16*)alloc(256 * 256 * 2);
  u16* fGn2     = (u16*)alloc(256 * 256 * 2);
  u16* fGo      = (u16*)alloc(256 * 256 * 2);
  u16* fQ0      = (u16*)alloc(256 * 256 * 2);
  u16* fKV0     = (u16*)alloc(512 * 256 * 2);
  u16* fQKV1    = (u16*)alloc(768 * 256 * 2);
  u16* fQKV2    = (u16*)alloc(768 * 256 * 2);
  u16* fO0      = (u16*)alloc(256 * 256 * 2);
  u16* fO1      = (u16*)alloc(256 * 256 * 2);
  u16* fO2      = (u16*)alloc(256 * 256 * 2);
  u16* fFin     = (u16*)alloc(384 * 256 * 2);
  float* bkv0   = (float*)alloc(512 * 4);
  float* bqkv1  = (float*)alloc(768 * 4);
  float* bqkv2  = (float*)alloc(768 * 4);
  u16* q1b      = (u16*)alloc(16 * 256 * 2);
  u16* agg_b    = (u16*)alloc(1024 * 256 * 2);
  u16* kv1      = (u16*)alloc(1024 * 512 * 2);
  float* o1f    = (float*)alloc(64 * 256 * 4);
  u16* o1b      = (u16*)alloc(64 * 256 * 2);
  int* bar      = (int*)alloc(256);

  PreArgs P{};
  int nj = 0, tiles = 0;
  auto addF = [&](const float* s, int stride, u16* d, int nT) {
    P.fsrc[nj] = s; P.fdst[nj] = d; P.fstride[nj] = stride; P.fbase[nj] = tiles;
    tiles += nT; nj++;
  };
  addF(geW1, 256, fWiWj, 16);
  addF(geW1 + 65536, 256, fWiWj + 16 * 4096, 16);
  addF(geW2, 256, fW2, 16);
  addF(gnW1, 256, fGn1, 16);
  addF(gnW2, 256, fGn2, 16);
  addF(goW, 256, fGo, 16);
  addF(mWq, 256, fQ0, 16);
  addF(mWk, 256, fKV0, 16);
  addF(mWv, 256, fKV0 + 16 * 4096, 16);
  addF(mWq + 65536, 256, fQKV1, 16);
  addF(mWk + 65536, 256, fQKV1 + 16 * 4096, 16);
  addF(mWv + 65536, 256, fQKV1 + 32 * 4096, 16);
  addF(mWq + 131072, 256, fQKV2, 16);
  addF(mWk + 131072, 256, fQKV2 + 16 * 4096, 16);
  addF(mWv + 131072, 256, fQKV2 + 32 * 4096, 16);
  addF(mWo, 256, fO0, 16);
  addF(mWo + 65536, 256, fO1, 16);
  addF(mWo + 131072, 256, fO2, 16);
  addF(finW, 384, fFin, 24);
  P.fbase[nj] = tiles;
  P.fragTiles = tiles;
  P.hBase = tiles;
  P.prepBid = tiles + 256;
  P.q1Bid = tiles + 257;
  P.x = x; P.ginW = ginW; P.ginb = ginb; P.h_bf = h_bf;
  P.mbk = mbk; P.mbv = mbv; P.mbq = mbq; P.S = S; P.mWq = mWq;
  P.bkv0 = bkv0; P.bqkv1 = bqkv1; P.bqkv2 = bqkv2; P.q1b = q1b;

  TailArgs T{};
  T.agg = agg_b; T.fGn1 = fGn1; T.fGn2 = fGn2; T.fGo = fGo; T.fKV0 = fKV0;
  T.fQKV1 = fQKV1; T.fQKV2 = fQKV2; T.fO0 = fO0; T.fO1 = fO1; T.fO2 = fO2;
  T.fFin = fFin; T.q1b = q1b;
  T.gnb1 = gnb1; T.gnb2 = gnb2; T.gob = gob;
  T.bkv0 = bkv0; T.bqkv1 = bqkv1; T.bqkv2 = bqkv2; T.mbo = mbo; T.finb = finb;
  T.kv1 = kv1; T.o1b = o1b; T.o1f = o1f; T.outF = (float*)d_out;
  T.bar = bar;

  hipMemsetAsync(bar, 0, 256, stream);
  k_pre<<<dim3(tiles + 258), dim3(256), 0, stream>>>(P);
  k_wiwj<<<dim3(16, 4), dim3(256), 0, stream>>>(h_bf, fWiWj, hWiWjf);
  k_edge<<<dim3(1024), dim3(256), 0, stream>>>(hWiWjf, adj, geb1, fW2, geb2, agg_b);
  k_tail<<<dim3(NBLK), dim3(256), 0, stream>>>(T);
}

// Round 11
// 243.514 us; speedup vs baseline: 2.1364x; 1.2594x over previous
//
#include <hip/hip_runtime.h>
#include <hip/hip_bf16.h>

typedef unsigned short u16;
typedef __bf16 bf8v __attribute__((ext_vector_type(8)));
typedef float f4v __attribute__((ext_vector_type(4)));

__device__ __forceinline__ float b2f(u16 v) {
  union { unsigned u; float f; } x; x.u = ((unsigned)v) << 16; return x.f;
}
__device__ __forceinline__ u16 f2b(float f) {
  union { float f; unsigned u; } x; x.f = f;
  unsigned r = (x.u + 0x7FFFu + ((x.u >> 16) & 1u)) >> 16;
  return (u16)r;
}
__device__ __forceinline__ unsigned pkbf(float a, float b) {
  union { __hip_bfloat162 h; unsigned u; } c;
  c.h = __float22bfloat162_rn(make_float2(a, b));
  return c.u;
}
__device__ __forceinline__ void up2(unsigned u, float& lo, float& hi) {
  union { unsigned x; float f; } a, b;
  a.x = u << 16; b.x = u & 0xffff0000u; lo = a.f; hi = b.f;
}

// ---------------------------------------------------------------------------
// Fragment-major weight layout: for weight W[k=0..255][n], tile T=n>>4:
// frag[((T*8+kt)*64+lane)*8 + j] = bf16(W[kt*32+(lane>>4)*8+j][T*16+(lane&15)])
// ---------------------------------------------------------------------------
#define NFRAG 19
struct PreArgs {
  const float* fsrc[NFRAG];
  u16* fdst[NFRAG];
  int fstride[NFRAG];
  int fbase[NFRAG + 1];
  int fragTiles, hBase, prepBid, q1Bid;
  const float *x, *ginW, *ginb;
  u16* h_bf;
  const float *mbk, *mbv, *mbq, *S, *mWq;
  float *bkv0, *bqkv1, *bqkv2;
  u16* q1b;
};

__global__ __launch_bounds__(256) void k_pre(PreArgs a) {
  __shared__ u16 ld[256 * 20];
  __shared__ float xs[4][48];
  __shared__ float Ss[4096];
  const int bid = blockIdx.x, t = threadIdx.x;

  if (bid < a.fragTiles) {
    int j = 0;
    while (j + 1 < NFRAG && a.fbase[j + 1] <= bid) j++;
    const int localT = bid - a.fbase[j];
    const float* src = a.fsrc[j];
    const int Ns = a.fstride[j];
    const int n0 = localT * 16;
    {
      const float* s = src + (size_t)t * Ns + n0;
      const float4 v0 = ((const float4*)s)[0], v1 = ((const float4*)s)[1];
      const float4 v2 = ((const float4*)s)[2], v3 = ((const float4*)s)[3];
      unsigned* row = (unsigned*)(ld + t * 20);
      row[0] = pkbf(v0.x, v0.y); row[1] = pkbf(v0.z, v0.w);
      row[2] = pkbf(v1.x, v1.y); row[3] = pkbf(v1.z, v1.w);
      row[4] = pkbf(v2.x, v2.y); row[5] = pkbf(v2.z, v2.w);
      row[6] = pkbf(v3.x, v3.y); row[7] = pkbf(v3.z, v3.w);
    }
    __syncthreads();
    u16* dst = a.fdst[j] + (size_t)localT * 4096;
#pragma unroll
    for (int s2 = 0; s2 < 2; s2++) {
      const int o = t * 2 + s2, kt = o >> 6, lane = o & 63;
      const int nlo = lane & 15, bk = kt * 32 + ((lane >> 4) << 3);
      union { u16 h[8]; uint4 q; } pk;
#pragma unroll
      for (int j2 = 0; j2 < 8; j2++) pk.h[j2] = ld[(bk + j2) * 20 + nlo];
      *(uint4*)(dst + (size_t)(kt * 64 + lane) * 8) = pk.q;
    }
    return;
  }
  if (bid >= a.hBase && bid < a.hBase + 256) {
    const int row0 = (bid - a.hBase) * 4;
    if (t < 192) {
      const int rr = t / 48, k = t % 48;
      xs[rr][k] = a.x[(size_t)(row0 + rr) * 48 + k];
    }
    __syncthreads();
    const float bias = a.ginb[t];
    float acc[4] = {bias, bias, bias, bias};
    for (int k = 0; k < 48; k++) {
      const float w = a.ginW[(size_t)k * 256 + t];
#pragma unroll
      for (int rr = 0; rr < 4; rr++) acc[rr] += xs[rr][k] * w;
    }
#pragma unroll
    for (int rr = 0; rr < 4; rr++) a.h_bf[(size_t)(row0 + rr) * 256 + t] = f2b(acc[rr]);
    return;
  }
  if (bid == a.prepBid) {
    a.bkv0[t] = a.mbk[t]; a.bkv0[256 + t] = a.mbv[t];
    a.bqkv1[t] = a.mbq[256 + t]; a.bqkv1[256 + t] = a.mbk[256 + t]; a.bqkv1[512 + t] = a.mbv[256 + t];
    a.bqkv2[t] = a.mbq[512 + t]; a.bqkv2[256 + t] = a.mbk[512 + t]; a.bqkv2[512 + t] = a.mbv[512 + t];
    return;
  }
  if (bid == a.q1Bid) {
    for (int idx = t; idx < 4096; idx += 256) Ss[idx] = a.S[idx];
    __syncthreads();
    float acc[16];
#pragma unroll
    for (int r = 0; r < 16; r++) acc[r] = 0.f;
    for (int k = 0; k < 256; k++) {
      const float w = a.mWq[(size_t)k * 256 + t];
#pragma unroll
      for (int r = 0; r < 16; r++) acc[r] += Ss[r * 256 + k] * w;
    }
    const float bq = a.mbq[t];
#pragma unroll
    for (int r = 0; r < 16; r++) a.q1b[r * 256 + t] = f2b(acc[r] + bq);
    return;
  }
}

// ---------------------------------------------------------------------------
// hWiWj GEMM: writes hWi as fp32 (1024x256) and hWj as bf16 (1024x256).
// ---------------------------------------------------------------------------
__global__ __launch_bounds__(256) void k_wiwj(
    const u16* __restrict__ h, const u16* __restrict__ frag,
    float* __restrict__ hWiF, u16* __restrict__ hWjB) {
  __shared__ __align__(16) u16 As[64 * 264];
  const int t = threadIdx.x, lane = t & 63, wv = t >> 6;
  const int m0 = blockIdx.x * 64, n0 = blockIdx.y * 128;
  {
    const int row = t >> 2, ch = t & 3;
#pragma unroll
    for (int s = 0; s < 8; s++)
      *(uint4*)(As + row * 264 + ch * 64 + s * 8) =
          *(const uint4*)(h + (size_t)(m0 + row) * 256 + ch * 64 + s * 8);
  }
  __syncthreads();
  f4v acc[4][2];
#pragma unroll
  for (int mt = 0; mt < 4; mt++)
#pragma unroll
    for (int nt = 0; nt < 2; nt++) acc[mt][nt] = (f4v){0.f, 0.f, 0.f, 0.f};
  const int Tw = (n0 >> 4) + wv * 2;
#pragma unroll
  for (int kt = 0; kt < 8; kt++) {
    bf8v af[4], bf[2];
#pragma unroll
    for (int mt = 0; mt < 4; mt++)
      af[mt] = *(const bf8v*)(As + (mt * 16 + (lane & 15)) * 264 + kt * 32 + ((lane >> 4) << 3));
#pragma unroll
    for (int nt = 0; nt < 2; nt++)
      bf[nt] = *(const bf8v*)(frag + ((size_t)((Tw + nt) * 8 + kt) * 64 + lane) * 8);
#pragma unroll
    for (int mt = 0; mt < 4; mt++)
#pragma unroll
      for (int nt = 0; nt < 2; nt++)
        acc[mt][nt] = __builtin_amdgcn_mfma_f32_16x16x32_bf16(af[mt], bf[nt], acc[mt][nt], 0, 0, 0);
  }
#pragma unroll
  for (int mt = 0; mt < 4; mt++)
#pragma unroll
    for (int nt = 0; nt < 2; nt++) {
      const int n = n0 + wv * 32 + nt * 16 + (lane & 15);
      const int mb = m0 + mt * 16 + ((lane >> 4) << 2);
#pragma unroll
      for (int r = 0; r < 4; r++) {
        if (n < 256)
          hWiF[(size_t)(mb + r) * 256 + n] = acc[mt][nt][r];
        else
          hWjB[(size_t)(mb + r) * 256 + (n - 256)] = f2b(acc[mt][nt][r]);
      }
    }
}

// ---------------------------------------------------------------------------
// Edge MLP + masked aggregation. (256,2): no spill (round-5 proven).
// hWj gathered in bf16 (half traffic). As: row stride 280, chunk stride 72
// (36 dwords — breaks the 4-way same-bank write conflict).
// ---------------------------------------------------------------------------
__global__ __launch_bounds__(256, 2) void k_edge(
    const float* __restrict__ hWiF, const u16* __restrict__ hWjB,
    const float* __restrict__ adj, const float* __restrict__ geb1,
    const u16* __restrict__ fragW2, const float* __restrict__ geb2,
    u16* __restrict__ aggB) {
  __shared__ __align__(16) u16 As[64 * 280];
  __shared__ float hi[256];
  __shared__ int jlist[256];
  __shared__ int cnt;
  const int t = threadIdx.x, lane = t & 63, wv = t >> 6;
  const int b = blockIdx.x >> 8, i = blockIdx.x & 255;
  if (t == 0) cnt = 0;
  __syncthreads();
  {
    const float a = adj[(size_t)(b * 256 + i) * 256 + t];
    hi[t] = hWiF[(size_t)(b * 256 + i) * 256 + t] + geb1[t];
    if (a != 0.f) { const int p = atomicAdd(&cnt, 1); jlist[p] = t; }
  }
  __syncthreads();
  const int nact = cnt;
  if (nact == 0) {
    if (lane < 16) {
#pragma unroll
      for (int nt = 0; nt < 4; nt++)
        aggB[(size_t)(b * 256 + i) * 256 + wv * 64 + nt * 16 + lane] = 0;
    }
    return;
  }
  const int nch = (nact + 63) >> 6;
  float bias2[4];
#pragma unroll
  for (int nt = 0; nt < 4; nt++) bias2[nt] = geb2[wv * 64 + nt * 16 + (lane & 15)];
  float aggAcc[4] = {0.f, 0.f, 0.f, 0.f};
  const u16* fw = fragW2 + lane * 8;

  for (int c = 0; c < nch; c++) {
    const int rows = min(64, nact - c * 64);
    {  // build A chunk: relu(bf16(hWj[j]) + hi) -> bf16 (half-traffic gather)
      const int r = t >> 2, q = t & 3;
      const bool valid = (r < rows);
      const int j = valid ? jlist[c * 64 + r] : jlist[0];
      const uint4* s4 = (const uint4*)(hWjB + (size_t)(b * 256 + j) * 256 + q * 64);
      u16* dstrow = As + r * 280 + q * 72;
#pragma unroll
      for (int ii = 0; ii < 8; ii++) {
        const uint4 v = s4[ii];
        const int k = q * 64 + ii * 8;
        float f0, f1, f2, f3, f4, f5, f6, f7;
        up2(v.x, f0, f1); up2(v.y, f2, f3); up2(v.z, f4, f5); up2(v.w, f6, f7);
        uint4 qd;
        qd.x = pkbf(fmaxf(f0 + hi[k + 0], 0.f), fmaxf(f1 + hi[k + 1], 0.f));
        qd.y = pkbf(fmaxf(f2 + hi[k + 2], 0.f), fmaxf(f3 + hi[k + 3], 0.f));
        qd.z = pkbf(fmaxf(f4 + hi[k + 4], 0.f), fmaxf(f5 + hi[k + 5], 0.f));
        qd.w = pkbf(fmaxf(f6 + hi[k + 6], 0.f), fmaxf(f7 + hi[k + 7], 0.f));
        *(uint4*)(dstrow + ii * 8) = qd;
      }
    }
    __syncthreads();
    f4v acc[4][4];
#pragma unroll
    for (int jt = 0; jt < 4; jt++)
#pragma unroll
      for (int nt = 0; nt < 4; nt++) acc[jt][nt] = (f4v){0.f, 0.f, 0.f, 0.f};
    bf8v bcur[4];
#pragma unroll
    for (int nt = 0; nt < 4; nt++)
      bcur[nt] = *(const bf8v*)(fw + (size_t)((wv * 4 + nt) * 8 + 0) * 512);
#pragma unroll
    for (int kt = 0; kt < 8; kt++) {
      bf8v bnxt[4];
      if (kt < 7) {
#pragma unroll
        for (int nt = 0; nt < 4; nt++)
          bnxt[nt] = *(const bf8v*)(fw + (size_t)((wv * 4 + nt) * 8 + kt + 1) * 512);
      }
      bf8v af[4];
      const int coff = (kt >> 1) * 72 + (kt & 1) * 32 + ((lane >> 4) << 3);
#pragma unroll
      for (int jt = 0; jt < 4; jt++)
        af[jt] = *(const bf8v*)(As + (jt * 16 + (lane & 15)) * 280 + coff);
#pragma unroll
      for (int nt = 0; nt < 4; nt++)
#pragma unroll
        for (int jt = 0; jt < 4; jt++)
          acc[jt][nt] = __builtin_amdgcn_mfma_f32_16x16x32_bf16(af[jt], bcur[nt], acc[jt][nt], 0, 0, 0);
      if (kt < 7) {
#pragma unroll
        for (int nt = 0; nt < 4; nt++) bcur[nt] = bnxt[nt];
      }
    }
    const int rbase = (lane >> 4) * 4;
#pragma unroll
    for (int nt = 0; nt < 4; nt++) {
      float s = 0.f;
#pragma unroll
      for (int jt = 0; jt < 4; jt++) {
        const int r0 = jt * 16 + rbase;
#pragma unroll
        for (int r = 0; r < 4; r++) {
          const float e = fmaxf(acc[jt][nt][r] + bias2[nt], 0.f);
          s += (r0 + r < rows) ? e : 0.f;
        }
      }
      s += __shfl_xor(s, 16);
      s += __shfl_xor(s, 32);
      aggAcc[nt] += s;
    }
    __syncthreads();
  }
  if (lane < 16) {
#pragma unroll
    for (int nt = 0; nt < 4; nt++) {
      const int n = wv * 64 + nt * 16 + lane;
      aggB[(size_t)(b * 256 + i) * 256 + n] = f2b(aggAcc[nt]);
    }
  }
}

// ---------------------------------------------------------------------------
// Fused tail v4 (unchanged from round 10): 32 blocks x 256 threads.
// ---------------------------------------------------------------------------
#define NBLK 32

__device__ __forceinline__ void gridbar(int* cnt, int gen) {
  __syncthreads();
  if (threadIdx.x == 0) {
    __threadfence();
    __hip_atomic_fetch_add(cnt, 1, __ATOMIC_RELAXED, __HIP_MEMORY_SCOPE_AGENT);
    int it = 0;
    while (__hip_atomic_load(cnt, __ATOMIC_RELAXED, __HIP_MEMORY_SCOPE_AGENT) < NBLK * gen) {
      __builtin_amdgcn_s_sleep(8);
      if (((++it) & 255) == 0)
        __hip_atomic_fetch_add(cnt, 0, __ATOMIC_RELAXED, __HIP_MEMORY_SCOPE_AGENT);
    }
    __threadfence();
  }
  __syncthreads();
}

__device__ void g32(const u16* Al, const u16* frag, const float* bias, int relu,
                    u16* Ol, int t) {
  const int lane = t & 63, wv = t >> 6;
  f4v acc[2][4];
#pragma unroll
  for (int mt = 0; mt < 2; mt++)
#pragma unroll
    for (int nt = 0; nt < 4; nt++) acc[mt][nt] = (f4v){0.f, 0.f, 0.f, 0.f};
#pragma unroll
  for (int kt = 0; kt < 8; kt++) {
    bf8v af[2], bf[4];
#pragma unroll
    for (int mt = 0; mt < 2; mt++)
      af[mt] = *(const bf8v*)(Al + (mt * 16 + (lane & 15)) * 264 + kt * 32 + ((lane >> 4) << 3));
#pragma unroll
    for (int nt = 0; nt < 4; nt++)
      bf[nt] = *(const bf8v*)(frag + ((size_t)((wv * 4 + nt) * 8 + kt) * 64 + lane) * 8);
#pragma unroll
    for (int mt = 0; mt < 2; mt++)
#pragma unroll
      for (int nt = 0; nt < 4; nt++)
        acc[mt][nt] = __builtin_amdgcn_mfma_f32_16x16x32_bf16(af[mt], bf[nt], acc[mt][nt], 0, 0, 0);
  }
#pragma unroll
  for (int mt = 0; mt < 2; mt++)
#pragma unroll
    for (int nt = 0; nt < 4; nt++) {
      const int col = wv * 64 + nt * 16 + (lane & 15);
      const float bv = bias[col];
#pragma unroll
      for (int r = 0; r < 4; r++) {
        const int row = mt * 16 + ((lane >> 4) << 2) + r;
        float v = acc[mt][nt][r] + bv;
        if (relu) v = fmaxf(v, 0.f);
        Ol[row * 264 + col] = f2b(v);
      }
    }
}

__device__ void g32kv(const u16* Al, const u16* frag, const float* bias,
                      u16* outG, int t) {
  const int lane = t & 63, wv = t >> 6;
  f4v acc[2][8];
#pragma unroll
  for (int mt = 0; mt < 2; mt++)
#pragma unroll
    for (int nt = 0; nt < 8; nt++) acc[mt][nt] = (f4v){0.f, 0.f, 0.f, 0.f};
#pragma unroll
  for (int kt = 0; kt < 8; kt++) {
    bf8v af[2];
#pragma unroll
    for (int mt = 0; mt < 2; mt++)
      af[mt] = *(const bf8v*)(Al + (mt * 16 + (lane & 15)) * 264 + kt * 32 + ((lane >> 4) << 3));
#pragma unroll
    for (int nt = 0; nt < 8; nt++) {
      const bf8v bf = *(const bf8v*)(frag + ((size_t)((wv * 8 + nt) * 8 + kt) * 64 + lane) * 8);
#pragma unroll
      for (int mt = 0; mt < 2; mt++)
        acc[mt][nt] = __builtin_amdgcn_mfma_f32_16x16x32_bf16(af[mt], bf, acc[mt][nt], 0, 0, 0);
    }
  }
#pragma unroll
  for (int mt = 0; mt < 2; mt++)
#pragma unroll
    for (int nt = 0; nt < 8; nt++) {
      const int col = wv * 128 + nt * 16 + (lane & 15);
      const float bv = bias[col];
#pragma unroll
      for (int r = 0; r < 4; r++) {
        const int row = mt * 16 + ((lane >> 4) << 2) + r;
        outG[(size_t)row * 512 + col] = f2b(acc[mt][nt][r] + bv);
      }
    }
}

__device__ void attn_tile(const u16* __restrict__ qbuf,
                          const u16* __restrict__ kbuf, const u16* __restrict__ vbuf,
                          float* __restrict__ oF, u16* __restrict__ oB,
                          int b, int hd, float* qs, float* sc, float* vs, int t) {
  const int lane = t & 63, wv = t >> 6;
  const int Lk = 256;
  if (t < 64) {
    const int row = t >> 2, part = t & 3;
    const uint4 q4 = *(const uint4*)(qbuf + (size_t)row * 256 + hd * 32 + part * 8);
    float f0, f1, f2, f3, f4, f5, f6, f7;
    up2(q4.x, f0, f1); up2(q4.y, f2, f3); up2(q4.z, f4, f5); up2(q4.w, f6, f7);
    float4* d = (float4*)(qs + row * 32 + part * 8);
    d[0] = make_float4(f0, f1, f2, f3);
    d[1] = make_float4(f4, f5, f6, f7);
  }
  __syncthreads();
  {
    float kv[32];
    const uint4* kp = (const uint4*)(kbuf + (size_t)(b * Lk + t) * 512 + hd * 32);
#pragma unroll
    for (int c4 = 0; c4 < 4; c4++) {
      const uint4 k4 = kp[c4];
      up2(k4.x, kv[c4 * 8 + 0], kv[c4 * 8 + 1]);
      up2(k4.y, kv[c4 * 8 + 2], kv[c4 * 8 + 3]);
      up2(k4.z, kv[c4 * 8 + 4], kv[c4 * 8 + 5]);
      up2(k4.w, kv[c4 * 8 + 6], kv[c4 * 8 + 7]);
    }
    for (int r = 0; r < 16; r++) {
      float s = 0.f;
#pragma unroll
      for (int d = 0; d < 32; d++) s += qs[r * 32 + d] * kv[d];
      sc[r * 256 + t] = s * 0.0625f;
    }
  }
  __syncthreads();
  for (int r = wv * 4; r < wv * 4 + 4; r++) {
    float v[4];
    float mx = -1e30f;
#pragma unroll
    for (int q2 = 0; q2 < 4; q2++) {
      v[q2] = sc[r * 256 + lane + q2 * 64];
      mx = fmaxf(mx, v[q2]);
    }
    for (int off = 32; off; off >>= 1) mx = fmaxf(mx, __shfl_xor(mx, off));
    float sum = 0.f;
#pragma unroll
    for (int q2 = 0; q2 < 4; q2++) { v[q2] = __expf(v[q2] - mx); sum += v[q2]; }
    for (int off = 32; off; off >>= 1) sum += __shfl_xor(sum, off);
    const float inv = 1.f / sum;
#pragma unroll
    for (int q2 = 0; q2 < 4; q2++) sc[r * 256 + lane + q2 * 64] = v[q2] * inv;
  }
  __syncthreads();
  for (int u = t; u < 1024; u += 256) {
    const int row = u >> 2, part = u & 3;
    const uint4 v4 = *(const uint4*)(vbuf + (size_t)(b * Lk + row) * 512 + hd * 32 + part * 8);
    float f0, f1, f2, f3, f4, f5, f6, f7;
    up2(v4.x, f0, f1); up2(v4.y, f2, f3); up2(v4.z, f4, f5); up2(v4.w, f6, f7);
    float4* d = (float4*)(vs + row * 32 + part * 8);
    d[0] = make_float4(f0, f1, f2, f3);
    d[1] = make_float4(f4, f5, f6, f7);
  }
  __syncthreads();
  const int r0 = t >> 5, d = t & 31;
  float a0 = qs[r0 * 32 + d], a1 = qs[(r0 + 8) * 32 + d];
#pragma unroll 4
  for (int j = 0; j < Lk; j++) {
    const float vv = vs[j * 32 + d];
    a0 += sc[r0 * 256 + j] * vv;
    a1 += sc[(r0 + 8) * 256 + j] * vv;
  }
  const int c0 = hd * 32 + d;
  oF[(size_t)(b * 16 + r0) * 256 + c0] = a0;
  oB[(size_t)(b * 16 + r0) * 256 + c0] = f2b(a0);
  oF[(size_t)(b * 16 + r0 + 8) * 256 + c0] = a1;
  oB[(size_t)(b * 16 + r0 + 8) * 256 + c0] = f2b(a1);
}

__device__ void wprojG(const u16* __restrict__ o1b, const float* __restrict__ o1f,
                       const u16* __restrict__ frag, const float* __restrict__ bias,
                       u16* actL, float* residL, int b, int T, int lane) {
  f4v acc = (f4v){0.f, 0.f, 0.f, 0.f};
  const u16* abase = o1b + (size_t)(b * 16 + (lane & 15)) * 256 + ((lane >> 4) << 3);
  const u16* fbase = frag + ((size_t)(T * 8) * 64 + lane) * 8;
#pragma unroll
  for (int kt = 0; kt < 8; kt++)
    acc = __builtin_amdgcn_mfma_f32_16x16x32_bf16(*(const bf8v*)(abase + kt * 32),
                                                  *(const bf8v*)(fbase + (size_t)kt * 512), acc, 0, 0, 0);
  const int col = T * 16 + (lane & 15);
  const float bv = bias[col];
#pragma unroll
  for (int r = 0; r < 4; r++) {
    const int row = ((lane >> 4) << 2) + r;
    const float v = fmaxf(acc[r] + bv, 0.f) + o1f[(size_t)(b * 16 + row) * 256 + col];
    residL[row * 256 + col] = v;
    actL[row * 264 + col] = f2b(v);
  }
}

__device__ void wprojQ(const u16* actL, const u16* __restrict__ frag,
                       const float* __restrict__ bias, u16* qkvL, int T, int lane) {
  f4v acc = (f4v){0.f, 0.f, 0.f, 0.f};
  const u16* abase = actL + (lane & 15) * 264 + ((lane >> 4) << 3);
  const u16* fbase = frag + ((size_t)(T * 8) * 64 + lane) * 8;
#pragma unroll
  for (int kt = 0; kt < 8; kt++)
    acc = __builtin_amdgcn_mfma_f32_16x16x32_bf16(*(const bf8v*)(abase + kt * 32),
                                                  *(const bf8v*)(fbase + (size_t)kt * 512), acc, 0, 0, 0);
  const int col = T * 16 + (lane & 15);
  const float bv = bias[col];
#pragma unroll
  for (int r = 0; r < 4; r++) {
    const int row = ((lane >> 4) << 2) + r;
    qkvL[row * 776 + col] = f2b(acc[r] + bv);
  }
}

__device__ void wprojR(const u16* actIn, const u16* __restrict__ frag,
                       const float* __restrict__ bias, u16* actOut, float* residL,
                       int T, int lane) {
  f4v acc = (f4v){0.f, 0.f, 0.f, 0.f};
  const u16* abase = actIn + (lane & 15) * 264 + ((lane >> 4) << 3);
  const u16* fbase = frag + ((size_t)(T * 8) * 64 + lane) * 8;
#pragma unroll
  for (int kt = 0; kt < 8; kt++)
    acc = __builtin_amdgcn_mfma_f32_16x16x32_bf16(*(const bf8v*)(abase + kt * 32),
                                                  *(const bf8v*)(fbase + (size_t)kt * 512), acc, 0, 0, 0);
  const int col = T * 16 + (lane & 15);
  const float bv = bias[col];
#pragma unroll
  for (int r = 0; r < 4; r++) {
    const int row = ((lane >> 4) << 2) + r;
    const float v = fmaxf(acc[r] + bv, 0.f) + residL[row * 256 + col];
    residL[row * 256 + col] = v;
    actOut[row * 264 + col] = f2b(v);
  }
}

__device__ void wprojF(const u16* actL, const u16* __restrict__ frag,
                       const float* __restrict__ bias, float* __restrict__ outG,
                       int T, int lane) {
  f4v acc = (f4v){0.f, 0.f, 0.f, 0.f};
  const u16* abase = actL + (lane & 15) * 264 + ((lane >> 4) << 3);
  const u16* fbase = frag + ((size_t)(T * 8) * 64 + lane) * 8;
#pragma unroll
  for (int kt = 0; kt < 8; kt++)
    acc = __builtin_amdgcn_mfma_f32_16x16x32_bf16(*(const bf8v*)(abase + kt * 32),
                                                  *(const bf8v*)(fbase + (size_t)kt * 512), acc, 0, 0, 0);
  const int col = T * 16 + (lane & 15);
  const float bv = bias[col];
#pragma unroll
  for (int r = 0; r < 4; r++) {
    const int row = ((lane >> 4) << 2) + r;
    outG[(size_t)row * 384 + col] = acc[r] + bv;
  }
}

__device__ void attnB(const u16* qkvL, float* residL, u16* actOut, float* ps,
                      int hd, int lane) {
  const int r = lane & 15, cg = lane >> 4;
  float qv[32];
  {
    const uint4* qp = (const uint4*)(qkvL + r * 776 + hd * 32);
#pragma unroll
    for (int c4 = 0; c4 < 4; c4++) {
      const uint4 q4 = qp[c4];
      up2(q4.x, qv[c4 * 8 + 0], qv[c4 * 8 + 1]);
      up2(q4.y, qv[c4 * 8 + 2], qv[c4 * 8 + 3]);
      up2(q4.z, qv[c4 * 8 + 4], qv[c4 * 8 + 5]);
      up2(q4.w, qv[c4 * 8 + 6], qv[c4 * 8 + 7]);
    }
  }
  float p[4];
#pragma unroll
  for (int c = 0; c < 4; c++) {
    const int cc = cg * 4 + c;
    const uint4* kp = (const uint4*)(qkvL + cc * 776 + 256 + hd * 32);
    float s = 0.f;
#pragma unroll
    for (int c4 = 0; c4 < 4; c4++) {
      const uint4 k4 = kp[c4];
      float k0, k1;
      up2(k4.x, k0, k1); s += qv[c4 * 8 + 0] * k0 + qv[c4 * 8 + 1] * k1;
      up2(k4.y, k0, k1); s += qv[c4 * 8 + 2] * k0 + qv[c4 * 8 + 3] * k1;
      up2(k4.z, k0, k1); s += qv[c4 * 8 + 4] * k0 + qv[c4 * 8 + 5] * k1;
      up2(k4.w, k0, k1); s += qv[c4 * 8 + 6] * k0 + qv[c4 * 8 + 7] * k1;
    }
    p[c] = s * 0.0625f;
  }
  float mx = fmaxf(fmaxf(p[0], p[1]), fmaxf(p[2], p[3]));
  mx = fmaxf(mx, __shfl_xor(mx, 16));
  mx = fmaxf(mx, __shfl_xor(mx, 32));
  float sum = 0.f;
#pragma unroll
  for (int c = 0; c < 4; c++) { p[c] = __expf(p[c] - mx); sum += p[c]; }
  sum += __shfl_xor(sum, 16);
  sum += __shfl_xor(sum, 32);
  const float inv = 1.f / sum;
#pragma unroll
  for (int c = 0; c < 4; c++) ps[r * 16 + cg * 4 + c] = p[c] * inv;
  float o[8];
#pragma unroll
  for (int j = 0; j < 8; j++) o[j] = qv[cg * 8 + j];
#pragma unroll
  for (int c = 0; c < 16; c++) {
    const float pv = ps[r * 16 + c];
    const uint4 v4 = *(const uint4*)(qkvL + c * 776 + 512 + hd * 32 + cg * 8);
    float v0, v1;
    up2(v4.x, v0, v1); o[0] += pv * v0; o[1] += pv * v1;
    up2(v4.y, v0, v1); o[2] += pv * v0; o[3] += pv * v1;
    up2(v4.z, v0, v1); o[4] += pv * v0; o[5] += pv * v1;
    up2(v4.w, v0, v1); o[6] += pv * v0; o[7] += pv * v1;
  }
  const int col0 = hd * 32 + cg * 8;
#pragma unroll
  for (int j = 0; j < 8; j++) residL[r * 256 + col0 + j] = o[j];
  unsigned* ob = (unsigned*)(actOut + r * 264 + col0);
  ob[0] = pkbf(o[0], o[1]); ob[1] = pkbf(o[2], o[3]);
  ob[2] = pkbf(o[4], o[5]); ob[3] = pkbf(o[6], o[7]);
}

struct TailArgs {
  const u16 *agg, *fGn1, *fGn2, *fGo, *fKV0, *fQKV1, *fQKV2, *fO0, *fO1, *fO2, *fFin, *q1b;
  const float *gnb1, *gnb2, *gob, *bkv0, *bqkv1, *bqkv2, *mbo, *finb;
  u16 *kv1, *o1b;
  float *o1f, *outF;
  int* bar;
};

__global__ __launch_bounds__(256) void k_tail(TailArgs a) {
  __shared__ __align__(16) char smem[62208];
  const int bid = blockIdx.x, t = threadIdx.x;
  const int lane = t & 63, w = t >> 6;

  {  // ---- phase 1 ----
    u16* actA = (u16*)smem;
    u16* actB = (u16*)(smem + 16896);
    const int r0 = bid * 32;
#pragma unroll
    for (int s = 0; s < 4; s++) {
      const int u = t * 4 + s, row = u >> 5, ch = u & 31;
      *(uint4*)(actA + row * 264 + ch * 8) =
          *(const uint4*)(a.agg + (size_t)(r0 + row) * 256 + ch * 8);
    }
    __syncthreads();
    g32(actA, a.fGn1, a.gnb1, 1, actB, t); __syncthreads();
    g32(actB, a.fGn2, a.gnb2, 1, actA, t); __syncthreads();
    g32(actA, a.fGo, a.gob, 0, actB, t); __syncthreads();
    g32kv(actB, a.fKV0, a.bkv0, a.kv1 + (size_t)r0 * 512, t);
  }
  gridbar(a.bar, 1);
  {  // ---- phase 2 ----
    float* qs = (float*)smem;
    float* sc = (float*)(smem + 2048);
    float* vs = (float*)(smem + 18432);
    attn_tile(a.q1b, a.kv1, a.kv1 + 256, a.o1f, a.o1b, bid >> 3, bid & 7, qs, sc, vs, t);
  }
  gridbar(a.bar, 2);
  if (bid >= 4) return;
  {  // ---- phase 3 ----
    const int b = bid;
    u16* act0 = (u16*)smem;
    u16* act1 = (u16*)(smem + 8448);
    u16* qkvL = (u16*)(smem + 16896);
    float* residL = (float*)(smem + 41728);
    float* psL = (float*)(smem + 58112);
    __syncthreads();
    for (int T = w; T < 16; T += 4) wprojG(a.o1b, a.o1f, a.fO0, a.mbo, act0, residL, b, T, lane);
    __syncthreads();
    for (int T = w; T < 48; T += 4) wprojQ(act0, a.fQKV1, a.bqkv1, qkvL, T, lane);
    __syncthreads();
    for (int hd = w; hd < 8; hd += 4) attnB(qkvL, residL, act1, psL + w * 256, hd, lane);
    __syncthreads();
    for (int T = w; T < 16; T += 4) wprojR(act1, a.fO1, a.mbo + 256, act0, residL, T, lane);
    __syncthreads();
    for (int T = w; T < 48; T += 4) wprojQ(act0, a.fQKV2, a.bqkv2, qkvL, T, lane);
    __syncthreads();
    for (int hd = w; hd < 8; hd += 4) attnB(qkvL, residL, act1, psL + w * 256, hd, lane);
    __syncthreads();
    for (int T = w; T < 16; T += 4) wprojR(act1, a.fO2, a.mbo + 512, act0, residL, T, lane);
    __syncthreads();
    for (int T = w; T < 24; T += 4)
      wprojF(act0, a.fFin, a.finb, a.outF + (size_t)b * 16 * 384, T, lane);
  }
}

// ---------------------------------------------------------------------------
extern "C" void kernel_launch(void* const* d_in, const int* in_sizes, int n_in,
                              void* d_out, int out_size, void* d_ws, size_t ws_size,
                              hipStream_t stream) {
  const float* x    = (const float*)d_in[0];
  const float* adj  = (const float*)d_in[1];
  const float* ginW = (const float*)d_in[2];
  const float* ginb = (const float*)d_in[3];
  const float* geW1 = (const float*)d_in[4];
  const float* geb1 = (const float*)d_in[5];
  const float* geW2 = (const float*)d_in[6];
  const float* geb2 = (const float*)d_in[7];
  const float* gnW1 = (const float*)d_in[8];
  const float* gnb1 = (const float*)d_in[9];
  const float* gnW2 = (const float*)d_in[10];
  const float* gnb2 = (const float*)d_in[11];
  const float* goW  = (const float*)d_in[12];
  const float* gob  = (const float*)d_in[13];
  const float* S    = (const float*)d_in[14];
  const float* mWq  = (const float*)d_in[15];
  const float* mbq  = (const float*)d_in[16];
  const float* mWk  = (const float*)d_in[17];
  const float* mbk  = (const float*)d_in[18];
  const float* mWv  = (const float*)d_in[19];
  const float* mbv  = (const float*)d_in[20];
  const float* mWo  = (const float*)d_in[21];
  const float* mbo  = (const float*)d_in[22];
  const float* finW = (const float*)d_in[23];
  const float* finb = (const float*)d_in[24];
  (void)in_sizes; (void)n_in; (void)out_size; (void)ws_size;

  char* wp = (char*)d_ws;
  size_t off = 0;
  auto alloc = [&](size_t bytes) -> char* {
    char* p = wp + off;
    off += (bytes + 255) & ~(size_t)255;
    return p;
  };
  u16* h_bf     = (u16*)alloc(1024 * 256 * 2);
  float* hWiF   = (float*)alloc((size_t)1024 * 256 * 4);
  u16* hWjB     = (u16*)alloc(1024 * 256 * 2);
  u16* fWiWj    = (u16*)alloc(512 * 256 * 2);
  u16* fW2      = (u16*)alloc(256 * 256 * 2);
  u16* fGn1     = (u16*)alloc(256 * 256 * 2);
  u16* fGn2     = (u16*)alloc(256 * 256 * 2);
  u16* fGo      = (u16*)alloc(256 * 256 * 2);
  u16* fQ0      = (u16*)alloc(256 * 256 * 2);
  u16* fKV0     = (u16*)alloc(512 * 256 * 2);
  u16* fQKV1    = (u16*)alloc(768 * 256 * 2);
  u16* fQKV2    = (u16*)alloc(768 * 256 * 2);
  u16* fO0      = (u16*)alloc(256 * 256 * 2);
  u16* fO1      = (u16*)alloc(256 * 256 * 2);
  u16* fO2      = (u16*)alloc(256 * 256 * 2);
  u16* fFin     = (u16*)alloc(384 * 256 * 2);
  float* bkv0   = (float*)alloc(512 * 4);
  float* bqkv1  = (float*)alloc(768 * 4);
  float* bqkv2  = (float*)alloc(768 * 4);
  u16* q1b      = (u16*)alloc(16 * 256 * 2);
  u16* agg_b    = (u16*)alloc(1024 * 256 * 2);
  u16* kv1      = (u16*)alloc(1024 * 512 * 2);
  float* o1f    = (float*)alloc(64 * 256 * 4);
  u16* o1b      = (u16*)alloc(64 * 256 * 2);
  int* bar      = (int*)alloc(256);

  PreArgs P{};
  int nj = 0, tiles = 0;
  auto addF = [&](const float* s, int stride, u16* d, int nT) {
    P.fsrc[nj] = s; P.fdst[nj] = d; P.fstride[nj] = stride; P.fbase[nj] = tiles;
    tiles += nT; nj++;
  };
  addF(geW1, 256, fWiWj, 16);
  addF(geW1 + 65536, 256, fWiWj + 16 * 4096, 16);
  addF(geW2, 256, fW2, 16);
  addF(gnW1, 256, fGn1, 16);
  addF(gnW2, 256, fGn2, 16);
  addF(goW, 256, fGo, 16);
  addF(mWq, 256, fQ0, 16);
  addF(mWk, 256, fKV0, 16);
  addF(mWv, 256, fKV0 + 16 * 4096, 16);
  addF(mWq + 65536, 256, fQKV1, 16);
  addF(mWk + 65536, 256, fQKV1 + 16 * 4096, 16);
  addF(mWv + 65536, 256, fQKV1 + 32 * 4096, 16);
  addF(mWq + 131072, 256, fQKV2, 16);
  addF(mWk + 131072, 256, fQKV2 + 16 * 4096, 16);
  addF(mWv + 131072, 256, fQKV2 + 32 * 4096, 16);
  addF(mWo, 256, fO0, 16);
  addF(mWo + 65536, 256, fO1, 16);
  addF(mWo + 131072, 256, fO2, 16);
  addF(finW, 384, fFin, 24);
  P.fbase[nj] = tiles;
  P.fragTiles = tiles;
  P.hBase = tiles;
  P.prepBid = tiles + 256;
  P.q1Bid = tiles + 257;
  P.x = x; P.ginW = ginW; P.ginb = ginb; P.h_bf = h_bf;
  P.mbk = mbk; P.mbv = mbv; P.mbq = mbq; P.S = S; P.mWq = mWq;
  P.bkv0 = bkv0; P.bqkv1 = bqkv1; P.bqkv2 = bqkv2; P.q1b = q1b;

  TailArgs T{};
  T.agg = agg_b; T.fGn1 = fGn1; T.fGn2 = fGn2; T.fGo = fGo; T.fKV0 = fKV0;
  T.fQKV1 = fQKV1; T.fQKV2 = fQKV2; T.fO0 = fO0; T.fO1 = fO1; T.fO2 = fO2;
  T.fFin = fFin; T.q1b = q1b;
  T.gnb1 = gnb1; T.gnb2 = gnb2; T.gob = gob;
  T.bkv0 = bkv0; T.bqkv1 = bqkv1; T.bqkv2 = bqkv2; T.mbo = mbo; T.finb = finb;
  T.kv1 = kv1; T.o1b = o1b; T.o1f = o1f; T.outF = (float*)d_out;
  T.bar = bar;

  hipMemsetAsync(bar, 0, 256, stream);
  k_pre<<<dim3(tiles + 258), dim3(256), 0, stream>>>(P);
  k_wiwj<<<dim3(16, 4), dim3(256), 0, stream>>>(h_bf, fWiWj, hWiF, hWjB);
  k_edge<<<dim3(1024), dim3(256), 0, stream>>>(hWiF, hWjB, adj, geb1, fW2, geb2, agg_b);
  k_tail<<<dim3(NBLK), dim3(256), 0, stream>>>(T);
}